// Round 4
// baseline (1504.745 us; speedup 1.0000x reference)
//
#include <hip/hip_runtime.h>
#include <hip/hip_bf16.h>

// FEAT=EMB=HID=64, VOCAB=32, N_GRAPHS=64. N,E from in_sizes.
// Feature tables are held in bf16 (ushort) to halve gather traffic; weights
// are staged in LDS as packed bf16 pairs (W,R) to double occupancy.

__device__ inline float bf2f(unsigned short h) {
    return __uint_as_float(((unsigned int)h) << 16);
}
__device__ inline unsigned short f2bf(float f) {
    unsigned int u = __float_as_uint(f);
    u = (u + 0x7fffu + ((u >> 16) & 1u)) >> 16;  // RNE
    return (unsigned short)u;
}
__device__ inline unsigned int packbf(float w, float r) {
    return (unsigned int)f2bf(w) | ((unsigned int)f2bf(r) << 16);
}

// ---------------- cast x (fp32) -> bf16 table ----------------
__global__ __launch_bounds__(256) void cast_bf16(const float* __restrict__ x,
                                                 unsigned short* __restrict__ xb, int n4) {
    int i = blockIdx.x * 256 + threadIdx.x;
    if (i < n4) {
        const float4 v = ((const float4*)x)[i];
        ushort4 o;
        o.x = f2bf(v.x); o.y = f2bf(v.y); o.z = f2bf(v.z); o.w = f2bf(v.w);
        ((ushort4*)xb)[i] = o;
    }
}

// ---------------- CSR build ----------------

__global__ __launch_bounds__(256) void hist_kernel(const int* __restrict__ dst,
                                                   int* __restrict__ deg, int E) {
    int e = blockIdx.x * 256 + threadIdx.x;
    if (e < E) atomicAdd(&deg[dst[e]], 1);
}

__global__ __launch_bounds__(256) void scan_a(const int* __restrict__ deg,
                                              int* __restrict__ incl,
                                              int* __restrict__ bsums, int N) {
    __shared__ int tmp[256];
    int i = blockIdx.x * 256 + threadIdx.x;
    int v = (i < N) ? deg[i] : 0;
    tmp[threadIdx.x] = v;
    __syncthreads();
    for (int off = 1; off < 256; off <<= 1) {
        int t = (threadIdx.x >= off) ? tmp[threadIdx.x - off] : 0;
        __syncthreads();
        tmp[threadIdx.x] += t;
        __syncthreads();
    }
    if (i < N) incl[i] = tmp[threadIdx.x];
    if (threadIdx.x == 255) bsums[blockIdx.x] = tmp[255];
}

__global__ __launch_bounds__(512) void scan_b(int* __restrict__ bsums, int nb) {
    __shared__ int tmp[512];
    int t = threadIdx.x;
    int v = (t < nb) ? bsums[t] : 0;
    tmp[t] = v;
    __syncthreads();
    for (int off = 1; off < 512; off <<= 1) {
        int u = (t >= off) ? tmp[t - off] : 0;
        __syncthreads();
        tmp[t] += u;
        __syncthreads();
    }
    if (t < nb) bsums[t] = tmp[t] - v;  // exclusive
}

__global__ __launch_bounds__(256) void scan_c(const int* __restrict__ deg,
                                              int* __restrict__ rowptr,  // incl on entry
                                              int* __restrict__ cursor,
                                              const int* __restrict__ bsums, int N) {
    int i = blockIdx.x * 256 + threadIdx.x;
    if (i < N) {
        int d = deg[i];
        int excl = rowptr[i] - d + bsums[blockIdx.x];
        rowptr[i] = excl;
        cursor[i] = excl;
        if (i == N - 1) rowptr[N] = excl + d;
    }
}

__global__ __launch_bounds__(256) void scatter_kernel(const int* __restrict__ src,
                                                      const int* __restrict__ dst,
                                                      int* __restrict__ cursor,
                                                      int* __restrict__ bucket, int E) {
    int e = blockIdx.x * 256 + threadIdx.x;
    if (e < E) {
        int d = dst[e];
        int pos = atomicAdd(&cursor[d], 1);
        bucket[pos] = src[e];
    }
}

// ---------------- Fused RGCN layer (bf16 tables) ----------------
// out[i] = relu( (mean_{j in N(i)} x[j]) @ W + x[i] @ root + b )
// One wave per node; lane = feature. Row gather = wave-uniform base + lane*2
// (coalesced 128B), 8 independent rows in flight. Weights in LDS as packed
// bf16 (W,R) pairs, 2 k-steps per ds_read_b64.
__global__ __launch_bounds__(256, 8) void rgcn_fused(const unsigned short* __restrict__ xb,
                                                     const int* __restrict__ rowptr,
                                                     const int* __restrict__ bucket,
                                                     const float* __restrict__ W,
                                                     const float* __restrict__ R,
                                                     const float* __restrict__ b,
                                                     unsigned short* __restrict__ outb,
                                                     int N) {
    __shared__ uint2 wr2[2048];  // [k2=0..31][lane]: x = pack(W[2k2][l],R[2k2][l]), y = k=2k2+1
    __shared__ float bl[64];
    for (int t = threadIdx.x; t < 2048; t += 256) {
        const int k2 = t >> 6, l = t & 63;
        uint2 p;
        p.x = packbf(W[(2 * k2 + 0) * 64 + l], R[(2 * k2 + 0) * 64 + l]);
        p.y = packbf(W[(2 * k2 + 1) * 64 + l], R[(2 * k2 + 1) * 64 + l]);
        wr2[t] = p;
    }
    if (threadIdx.x < 64) bl[threadIdx.x] = b[threadIdx.x];
    __syncthreads();

    const int lane = threadIdx.x & 63;
    const int wid = threadIdx.x >> 6;
    const int gw = blockIdx.x * 4 + wid;
    const int nw = gridDim.x * 4;

    for (int i = gw; i < N; i += nw) {
        const int r0 = rowptr[i];
        const int dg = rowptr[i + 1] - r0;
        float a0 = 0.f, a1 = 0.f, a2 = 0.f, a3 = 0.f;
        for (int base = 0; base < dg; base += 64) {
            int m = dg - base;
            if (m > 64) m = 64;
            int s = (lane < m) ? bucket[r0 + base + lane] : 0;
            int j = 0;
            for (; j + 8 <= m; j += 8) {
                const int s0 = __shfl(s, j + 0), s1 = __shfl(s, j + 1);
                const int s2 = __shfl(s, j + 2), s3 = __shfl(s, j + 3);
                const int s4 = __shfl(s, j + 4), s5 = __shfl(s, j + 5);
                const int s6 = __shfl(s, j + 6), s7 = __shfl(s, j + 7);
                const unsigned short u0 = xb[(size_t)s0 * 64 + lane];
                const unsigned short u1 = xb[(size_t)s1 * 64 + lane];
                const unsigned short u2 = xb[(size_t)s2 * 64 + lane];
                const unsigned short u3 = xb[(size_t)s3 * 64 + lane];
                const unsigned short u4 = xb[(size_t)s4 * 64 + lane];
                const unsigned short u5 = xb[(size_t)s5 * 64 + lane];
                const unsigned short u6 = xb[(size_t)s6 * 64 + lane];
                const unsigned short u7 = xb[(size_t)s7 * 64 + lane];
                a0 += bf2f(u0); a1 += bf2f(u1); a2 += bf2f(u2); a3 += bf2f(u3);
                a0 += bf2f(u4); a1 += bf2f(u5); a2 += bf2f(u6); a3 += bf2f(u7);
            }
            if (j + 4 <= m) {
                const int s0 = __shfl(s, j + 0), s1 = __shfl(s, j + 1);
                const int s2 = __shfl(s, j + 2), s3 = __shfl(s, j + 3);
                const unsigned short u0 = xb[(size_t)s0 * 64 + lane];
                const unsigned short u1 = xb[(size_t)s1 * 64 + lane];
                const unsigned short u2 = xb[(size_t)s2 * 64 + lane];
                const unsigned short u3 = xb[(size_t)s3 * 64 + lane];
                a0 += bf2f(u0); a1 += bf2f(u1); a2 += bf2f(u2); a3 += bf2f(u3);
                j += 4;
            }
            for (; j < m; ++j) {
                a0 += bf2f(xb[(size_t)__shfl(s, j) * 64 + lane]);
            }
        }
        const float acc = (a0 + a1) + (a2 + a3);
        const float inv = 1.0f / (float)(dg > 0 ? dg : 1);
        const float av = acc * inv;
        const float xv = bf2f(xb[(size_t)i * 64 + lane]);

        float o = bl[lane];
#pragma unroll
        for (int k2 = 0; k2 < 32; ++k2) {
            const uint2 p = wr2[k2 * 64 + lane];
            const float wf0 = __uint_as_float(p.x << 16);
            const float rf0 = __uint_as_float(p.x & 0xffff0000u);
            const float wf1 = __uint_as_float(p.y << 16);
            const float rf1 = __uint_as_float(p.y & 0xffff0000u);
            const float av0 = __shfl(av, 2 * k2 + 0), av1 = __shfl(av, 2 * k2 + 1);
            const float xv0 = __shfl(xv, 2 * k2 + 0), xv1 = __shfl(xv, 2 * k2 + 1);
            o += av0 * wf0 + xv0 * rf0;
            o += av1 * wf1 + xv1 * rf1;
        }
        outb[(size_t)i * 64 + lane] = f2bf(fmaxf(o, 0.f));
    }
}

// ---------------- Pooling (batch sorted): bounds + per-graph block sum ----------
__global__ __launch_bounds__(128) void graph_bounds(const int* __restrict__ batch,
                                                    int* __restrict__ gstart, int N) {
    int t = threadIdx.x;
    if (t > 64) return;
    if (t == 64) { gstart[64] = N; return; }
    int lo = 0, hi = N;
    while (lo < hi) {
        int mid = (lo + hi) >> 1;
        if (batch[mid] < t) lo = mid + 1; else hi = mid;
    }
    gstart[t] = lo;
}

__global__ __launch_bounds__(256) void pool_kernel(const unsigned short* __restrict__ h,
                                                   const int* __restrict__ gstart,
                                                   float* __restrict__ pooled) {
    __shared__ float red[16][64];
    const int gph = blockIdx.x;
    const int r0 = gstart[gph], r1 = gstart[gph + 1];
    const int f = threadIdx.x & 15;
    const int r = threadIdx.x >> 4;
    float4 acc = {0.f, 0.f, 0.f, 0.f};
    for (int row = r0 + r; row < r1; row += 16) {
        const ushort4 v = *(const ushort4*)&h[(size_t)row * 64 + f * 4];
        acc.x += bf2f(v.x); acc.y += bf2f(v.y);
        acc.z += bf2f(v.z); acc.w += bf2f(v.w);
    }
    red[r][f * 4 + 0] = acc.x; red[r][f * 4 + 1] = acc.y;
    red[r][f * 4 + 2] = acc.z; red[r][f * 4 + 3] = acc.w;
    __syncthreads();
    if (threadIdx.x < 64) {
        float s = 0.f;
        for (int j = 0; j < 16; ++j) s += red[j][threadIdx.x];
        const int cnt = r1 - r0;
        const float invc = 1.0f / (float)(cnt > 0 ? cnt : 1);
        pooled[gph * 64 + threadIdx.x] = s * invc;  // mean directly
    }
}

// ---------------- Heads ----------------
__global__ __launch_bounds__(256) void head_kernel(const float* __restrict__ pooled,
                                                   const float* __restrict__ Wh,
                                                   const float* __restrict__ bh,
                                                   const float* __restrict__ Wc,
                                                   const float* __restrict__ bc,
                                                   const float* __restrict__ Wo,
                                                   const float* __restrict__ bo,
                                                   float* __restrict__ out) {
    __shared__ float pm[4096];
    __shared__ float hid[4096];
    __shared__ float lg[2048];
    const int t = threadIdx.x;

    for (int idx = t; idx < 4096; idx += 256) pm[idx] = pooled[idx];
    __syncthreads();

    for (int idx = t; idx < 4096; idx += 256) {
        int g = idx >> 6, o = idx & 63;
        float ah = bh[o], ac = bc[o];
        for (int k = 0; k < 64; ++k) {
            float p = pm[(g << 6) + k];
            ah += p * Wh[k * 64 + o];
            ac += p * Wc[k * 64 + o];
        }
        hid[idx] = ah;
        out[2048 + idx] = ah;  // hidden
        out[6144 + idx] = ac;  // cell
    }
    __syncthreads();

    for (int idx = t; idx < 2048; idx += 256) {
        int g = idx >> 5, v = idx & 31;
        float a = bo[v];
        for (int k = 0; k < 64; ++k) a += hid[(g << 6) + k] * Wo[k * 32 + v];
        lg[idx] = a;
    }
    __syncthreads();

    if (t < 64) {
        float mx = -3.4e38f;
        for (int v = 0; v < 32; ++v) mx = fmaxf(mx, lg[(t << 5) + v]);
        float s = 0.f;
        for (int v = 0; v < 32; ++v) s += expf(lg[(t << 5) + v] - mx);
        float lse = mx + logf(s);
        for (int v = 0; v < 32; ++v) out[(t << 5) + v] = lg[(t << 5) + v] - lse;
    }
}

extern "C" void kernel_launch(void* const* d_in, const int* in_sizes, int n_in,
                              void* d_out, int out_size, void* d_ws, size_t ws_size,
                              hipStream_t stream) {
    const float* x = (const float*)d_in[0];
    const int* ei = (const int*)d_in[1];
    const int* batch = (const int*)d_in[2];
    const float* W1 = (const float*)d_in[3];
    const float* root1 = (const float*)d_in[4];
    const float* b1 = (const float*)d_in[5];
    const float* W2 = (const float*)d_in[6];
    const float* root2 = (const float*)d_in[7];
    const float* b2 = (const float*)d_in[8];
    const float* Wh = (const float*)d_in[9];
    const float* bh = (const float*)d_in[10];
    const float* Wc = (const float*)d_in[11];
    const float* bc = (const float*)d_in[12];
    const float* Wo = (const float*)d_in[13];
    const float* bo = (const float*)d_in[14];
    float* out = (float*)d_out;

    const int N = in_sizes[0] / 64;
    const int E = in_sizes[1] / 2;
    const int* srcp = ei;
    const int* dstp = ei + E;

    char* ws = (char*)d_ws;
    size_t off = 0;
    auto alloc = [&](size_t bytes) -> void* {
        void* p = ws + off;
        off += (bytes + 255) & ~(size_t)255;
        return p;
    };
    int* deg = (int*)alloc((size_t)N * 4);
    int* rowptr = (int*)alloc((size_t)(N + 1) * 4);
    int* cursor = (int*)alloc((size_t)N * 4);
    int* bsums = (int*)alloc(512 * 4);
    int* bucket = (int*)alloc((size_t)E * 4);
    unsigned short* xb = (unsigned short*)alloc((size_t)N * 64 * 2);
    unsigned short* h1 = (unsigned short*)alloc((size_t)N * 64 * 2);
    unsigned short* h2 = (unsigned short*)alloc((size_t)N * 64 * 2);
    float* pooled = (float*)alloc(4096 * 4);
    int* gstart = (int*)alloc(65 * 4);

    const int nbN = (N + 255) / 256;
    const int nbE = (E + 255) / 256;
    const int n4 = N * 16;  // N*64/4

    hipMemsetAsync(deg, 0, (size_t)N * 4, stream);

    cast_bf16<<<(n4 + 255) / 256, 256, 0, stream>>>(x, xb, n4);
    hist_kernel<<<nbE, 256, 0, stream>>>(dstp, deg, E);
    scan_a<<<nbN, 256, 0, stream>>>(deg, rowptr, bsums, N);
    scan_b<<<1, 512, 0, stream>>>(bsums, nbN);
    scan_c<<<nbN, 256, 0, stream>>>(deg, rowptr, cursor, bsums, N);
    scatter_kernel<<<nbE, 256, 0, stream>>>(srcp, dstp, cursor, bucket, E);

    rgcn_fused<<<2048, 256, 0, stream>>>(xb, rowptr, bucket, W1, root1, b1, h1, N);
    rgcn_fused<<<2048, 256, 0, stream>>>(h1, rowptr, bucket, W2, root2, b2, h2, N);

    graph_bounds<<<1, 128, 0, stream>>>(batch, gstart, N);
    pool_kernel<<<64, 256, 0, stream>>>(h2, gstart, pooled);
    head_kernel<<<1, 256, 0, stream>>>(pooled, Wh, bh, Wc, bc, Wo, bo, out);
}

// Round 5
// 787.696 us; speedup vs baseline: 1.9103x; 1.9103x over previous
//
#include <hip/hip_runtime.h>
#include <hip/hip_bf16.h>

// FEAT=EMB=HID=64, VOCAB=32, N_GRAPHS=64. N,E from in_sizes.
// Feature tables in bf16 (halves logical gather bytes), but ALL accesses are
// >= dword per lane: sub-dword gathers cost ~16B fetch granule per lane
// (measured R4: 1.66GB fetch for 205MB logical). Rows are read as
// 32-lane x dword, two rows per wave instruction.

__device__ inline float bf2f(unsigned short h) {
    return __uint_as_float(((unsigned int)h) << 16);
}
__device__ inline float bflo(unsigned int u) {
    return __uint_as_float(u << 16);
}
__device__ inline float bfhi(unsigned int u) {
    return __uint_as_float(u & 0xffff0000u);
}
__device__ inline unsigned short f2bf(float f) {
    unsigned int u = __float_as_uint(f);
    u = (u + 0x7fffu + ((u >> 16) & 1u)) >> 16;  // RNE
    return (unsigned short)u;
}
__device__ inline unsigned int packbf(float w, float r) {
    return (unsigned int)f2bf(w) | ((unsigned int)f2bf(r) << 16);
}

// ---------------- cast x (fp32) -> bf16 table ----------------
__global__ __launch_bounds__(256) void cast_bf16(const float* __restrict__ x,
                                                 unsigned short* __restrict__ xb, int n4) {
    int i = blockIdx.x * 256 + threadIdx.x;
    if (i < n4) {
        const float4 v = ((const float4*)x)[i];
        ushort4 o;
        o.x = f2bf(v.x); o.y = f2bf(v.y); o.z = f2bf(v.z); o.w = f2bf(v.w);
        ((ushort4*)xb)[i] = o;
    }
}

// ---------------- CSR build ----------------

__global__ __launch_bounds__(256) void hist_kernel(const int* __restrict__ dst,
                                                   int* __restrict__ deg, int E) {
    int e = blockIdx.x * 256 + threadIdx.x;
    if (e < E) atomicAdd(&deg[dst[e]], 1);
}

__global__ __launch_bounds__(256) void scan_a(const int* __restrict__ deg,
                                              int* __restrict__ incl,
                                              int* __restrict__ bsums, int N) {
    __shared__ int tmp[256];
    int i = blockIdx.x * 256 + threadIdx.x;
    int v = (i < N) ? deg[i] : 0;
    tmp[threadIdx.x] = v;
    __syncthreads();
    for (int off = 1; off < 256; off <<= 1) {
        int t = (threadIdx.x >= off) ? tmp[threadIdx.x - off] : 0;
        __syncthreads();
        tmp[threadIdx.x] += t;
        __syncthreads();
    }
    if (i < N) incl[i] = tmp[threadIdx.x];
    if (threadIdx.x == 255) bsums[blockIdx.x] = tmp[255];
}

__global__ __launch_bounds__(512) void scan_b(int* __restrict__ bsums, int nb) {
    __shared__ int tmp[512];
    int t = threadIdx.x;
    int v = (t < nb) ? bsums[t] : 0;
    tmp[t] = v;
    __syncthreads();
    for (int off = 1; off < 512; off <<= 1) {
        int u = (t >= off) ? tmp[t - off] : 0;
        __syncthreads();
        tmp[t] += u;
        __syncthreads();
    }
    if (t < nb) bsums[t] = tmp[t] - v;  // exclusive
}

__global__ __launch_bounds__(256) void scan_c(const int* __restrict__ deg,
                                              int* __restrict__ rowptr,  // incl on entry
                                              int* __restrict__ cursor,
                                              const int* __restrict__ bsums, int N) {
    int i = blockIdx.x * 256 + threadIdx.x;
    if (i < N) {
        int d = deg[i];
        int excl = rowptr[i] - d + bsums[blockIdx.x];
        rowptr[i] = excl;
        cursor[i] = excl;
        if (i == N - 1) rowptr[N] = excl + d;
    }
}

__global__ __launch_bounds__(256) void scatter_kernel(const int* __restrict__ src,
                                                      const int* __restrict__ dst,
                                                      int* __restrict__ cursor,
                                                      int* __restrict__ bucket, int E) {
    int e = blockIdx.x * 256 + threadIdx.x;
    if (e < E) {
        int d = dst[e];
        int pos = atomicAdd(&cursor[d], 1);
        bucket[pos] = src[e];
    }
}

// ---------------- Fused RGCN layer (bf16 tables, dword accesses) ----------------
// out[i] = relu( (mean_{j in N(i)} x[j]) @ W + x[i] @ root + b )
// One wave per node. A bf16 row (128B) is read by a 32-lane half-wave as
// dwords; each load instruction covers 2 rows (one per half). 16-row unroll
// = 8 independent loads in flight per wave.
__global__ __launch_bounds__(256) void rgcn_fused(const unsigned short* __restrict__ xb,
                                                  const int* __restrict__ rowptr,
                                                  const int* __restrict__ bucket,
                                                  const float* __restrict__ W,
                                                  const float* __restrict__ R,
                                                  const float* __restrict__ b,
                                                  unsigned short* __restrict__ outb,
                                                  int N) {
    __shared__ uint2 wr2[2048];  // [k2][lane]: x=pack(W[2k2][l],R[2k2][l]), y=k=2k2+1
    __shared__ float bl[64];
    for (int t = threadIdx.x; t < 2048; t += 256) {
        const int k2 = t >> 6, l = t & 63;
        uint2 p;
        p.x = packbf(W[(2 * k2 + 0) * 64 + l], R[(2 * k2 + 0) * 64 + l]);
        p.y = packbf(W[(2 * k2 + 1) * 64 + l], R[(2 * k2 + 1) * 64 + l]);
        wr2[t] = p;
    }
    if (threadIdx.x < 64) bl[threadIdx.x] = b[threadIdx.x];
    __syncthreads();

    const int lane = threadIdx.x & 63;
    const int half = lane >> 5;   // 0: row A, 1: row B
    const int fl = lane & 31;     // feature-pair index (feats 2fl, 2fl+1)
    const int wid = threadIdx.x >> 6;
    const int gw = blockIdx.x * 4 + wid;
    const int nw = gridDim.x * 4;

    for (int i = gw; i < N; i += nw) {
        const int r0 = rowptr[i];
        const int dg = rowptr[i + 1] - r0;
        float lo0 = 0.f, lo1 = 0.f, hi0 = 0.f, hi1 = 0.f;
        for (int base = 0; base < dg; base += 64) {
            int m = dg - base;
            if (m > 64) m = 64;
            int s = (lane < m) ? bucket[r0 + base + lane] : 0;
            int j = 0;
            for (; j + 16 <= m; j += 16) {
                unsigned int u0, u1, u2, u3, u4, u5, u6, u7;
#define ROW2(uu, jj)                                                              \
    {                                                                             \
        const int ra_ = __shfl(s, (jj)), rb_ = __shfl(s, (jj) + 1);               \
        const int rr_ = half ? rb_ : ra_;                                         \
        uu = *(const unsigned int*)&xb[(size_t)rr_ * 64 + fl * 2];                \
    }
                ROW2(u0, j + 0) ROW2(u1, j + 2) ROW2(u2, j + 4) ROW2(u3, j + 6)
                ROW2(u4, j + 8) ROW2(u5, j + 10) ROW2(u6, j + 12) ROW2(u7, j + 14)
                lo0 += bflo(u0); hi0 += bfhi(u0);
                lo1 += bflo(u1); hi1 += bfhi(u1);
                lo0 += bflo(u2); hi0 += bfhi(u2);
                lo1 += bflo(u3); hi1 += bfhi(u3);
                lo0 += bflo(u4); hi0 += bfhi(u4);
                lo1 += bflo(u5); hi1 += bfhi(u5);
                lo0 += bflo(u6); hi0 += bfhi(u6);
                lo1 += bflo(u7); hi1 += bfhi(u7);
            }
            for (; j + 2 <= m; j += 2) {
                unsigned int u;
                ROW2(u, j)
                lo0 += bflo(u); hi0 += bfhi(u);
            }
            if (j < m) {  // single leftover row: upper half contributes 0
                const int ra = __shfl(s, j);
                const unsigned int u = *(const unsigned int*)&xb[(size_t)ra * 64 + fl * 2];
                const float w = half ? 0.f : 1.f;
                lo0 += w * bflo(u); hi0 += w * bfhi(u);
            }
#undef ROW2
        }
        float lo = lo0 + lo1, hi = hi0 + hi1;
        lo += __shfl_xor(lo, 32);  // fold the two half-waves; all lanes get totals
        hi += __shfl_xor(hi, 32);

        const float inv = 1.0f / (float)(dg > 0 ? dg : 1);
        const float avLo = lo * inv, avHi = hi * inv;
        // self row, read as dwords too (both halves load same line set)
        const unsigned int su = *(const unsigned int*)&xb[(size_t)i * 64 + fl * 2];
        const float xvLo = bflo(su), xvHi = bfhi(su);

        float o = bl[lane];
#pragma unroll
        for (int k2 = 0; k2 < 32; ++k2) {
            const uint2 p = wr2[k2 * 64 + lane];
            const float wf0 = bflo(p.x), rf0 = bfhi(p.x);
            const float wf1 = bflo(p.y), rf1 = bfhi(p.y);
            const float av0 = __shfl(avLo, k2), av1 = __shfl(avHi, k2);
            const float xv0 = __shfl(xvLo, k2), xv1 = __shfl(xvHi, k2);
            o += av0 * wf0 + xv0 * rf0;
            o += av1 * wf1 + xv1 * rf1;
        }
        o = fmaxf(o, 0.f);
        // paired-bf16 dword store: even lanes store {o[lane], o[lane+1]}
        const float onext = __shfl_down(o, 1);
        if (!(lane & 1)) {
            const unsigned int u = (unsigned int)f2bf(o) | ((unsigned int)f2bf(onext) << 16);
            *(unsigned int*)&outb[(size_t)i * 64 + lane] = u;
        }
    }
}

// ---------------- Pooling (batch sorted): bounds + per-graph block sum ----------
__global__ __launch_bounds__(128) void graph_bounds(const int* __restrict__ batch,
                                                    int* __restrict__ gstart, int N) {
    int t = threadIdx.x;
    if (t > 64) return;
    if (t == 64) { gstart[64] = N; return; }
    int lo = 0, hi = N;
    while (lo < hi) {
        int mid = (lo + hi) >> 1;
        if (batch[mid] < t) lo = mid + 1; else hi = mid;
    }
    gstart[t] = lo;
}

__global__ __launch_bounds__(256) void pool_kernel(const unsigned short* __restrict__ h,
                                                   const int* __restrict__ gstart,
                                                   float* __restrict__ pooled) {
    __shared__ float red[16][64];
    const int gph = blockIdx.x;
    const int r0 = gstart[gph], r1 = gstart[gph + 1];
    const int f = threadIdx.x & 15;
    const int r = threadIdx.x >> 4;
    float4 acc = {0.f, 0.f, 0.f, 0.f};
    for (int row = r0 + r; row < r1; row += 16) {
        const ushort4 v = *(const ushort4*)&h[(size_t)row * 64 + f * 4];
        acc.x += bf2f(v.x); acc.y += bf2f(v.y);
        acc.z += bf2f(v.z); acc.w += bf2f(v.w);
    }
    red[r][f * 4 + 0] = acc.x; red[r][f * 4 + 1] = acc.y;
    red[r][f * 4 + 2] = acc.z; red[r][f * 4 + 3] = acc.w;
    __syncthreads();
    if (threadIdx.x < 64) {
        float s = 0.f;
        for (int j = 0; j < 16; ++j) s += red[j][threadIdx.x];
        const int cnt = r1 - r0;
        const float invc = 1.0f / (float)(cnt > 0 ? cnt : 1);
        pooled[gph * 64 + threadIdx.x] = s * invc;  // mean directly
    }
}

// ---------------- Heads ----------------
__global__ __launch_bounds__(256) void head_kernel(const float* __restrict__ pooled,
                                                   const float* __restrict__ Wh,
                                                   const float* __restrict__ bh,
                                                   const float* __restrict__ Wc,
                                                   const float* __restrict__ bc,
                                                   const float* __restrict__ Wo,
                                                   const float* __restrict__ bo,
                                                   float* __restrict__ out) {
    __shared__ float pm[4096];
    __shared__ float hid[4096];
    __shared__ float lg[2048];
    const int t = threadIdx.x;

    for (int idx = t; idx < 4096; idx += 256) pm[idx] = pooled[idx];
    __syncthreads();

    for (int idx = t; idx < 4096; idx += 256) {
        int g = idx >> 6, o = idx & 63;
        float ah = bh[o], ac = bc[o];
        for (int k = 0; k < 64; ++k) {
            float p = pm[(g << 6) + k];
            ah += p * Wh[k * 64 + o];
            ac += p * Wc[k * 64 + o];
        }
        hid[idx] = ah;
        out[2048 + idx] = ah;  // hidden
        out[6144 + idx] = ac;  // cell
    }
    __syncthreads();

    for (int idx = t; idx < 2048; idx += 256) {
        int g = idx >> 5, v = idx & 31;
        float a = bo[v];
        for (int k = 0; k < 64; ++k) a += hid[(g << 6) + k] * Wo[k * 32 + v];
        lg[idx] = a;
    }
    __syncthreads();

    if (t < 64) {
        float mx = -3.4e38f;
        for (int v = 0; v < 32; ++v) mx = fmaxf(mx, lg[(t << 5) + v]);
        float s = 0.f;
        for (int v = 0; v < 32; ++v) s += expf(lg[(t << 5) + v] - mx);
        float lse = mx + logf(s);
        for (int v = 0; v < 32; ++v) out[(t << 5) + v] = lg[(t << 5) + v] - lse;
    }
}

extern "C" void kernel_launch(void* const* d_in, const int* in_sizes, int n_in,
                              void* d_out, int out_size, void* d_ws, size_t ws_size,
                              hipStream_t stream) {
    const float* x = (const float*)d_in[0];
    const int* ei = (const int*)d_in[1];
    const int* batch = (const int*)d_in[2];
    const float* W1 = (const float*)d_in[3];
    const float* root1 = (const float*)d_in[4];
    const float* b1 = (const float*)d_in[5];
    const float* W2 = (const float*)d_in[6];
    const float* root2 = (const float*)d_in[7];
    const float* b2 = (const float*)d_in[8];
    const float* Wh = (const float*)d_in[9];
    const float* bh = (const float*)d_in[10];
    const float* Wc = (const float*)d_in[11];
    const float* bc = (const float*)d_in[12];
    const float* Wo = (const float*)d_in[13];
    const float* bo = (const float*)d_in[14];
    float* out = (float*)d_out;

    const int N = in_sizes[0] / 64;
    const int E = in_sizes[1] / 2;
    const int* srcp = ei;
    const int* dstp = ei + E;

    char* ws = (char*)d_ws;
    size_t off = 0;
    auto alloc = [&](size_t bytes) -> void* {
        void* p = ws + off;
        off += (bytes + 255) & ~(size_t)255;
        return p;
    };
    int* deg = (int*)alloc((size_t)N * 4);
    int* rowptr = (int*)alloc((size_t)(N + 1) * 4);
    int* cursor = (int*)alloc((size_t)N * 4);
    int* bsums = (int*)alloc(512 * 4);
    int* bucket = (int*)alloc((size_t)E * 4);
    unsigned short* xb = (unsigned short*)alloc((size_t)N * 64 * 2);
    unsigned short* h1 = (unsigned short*)alloc((size_t)N * 64 * 2);
    unsigned short* h2 = (unsigned short*)alloc((size_t)N * 64 * 2);
    float* pooled = (float*)alloc(4096 * 4);
    int* gstart = (int*)alloc(65 * 4);

    const int nbN = (N + 255) / 256;
    const int nbE = (E + 255) / 256;
    const int n4 = N * 16;  // N*64/4

    hipMemsetAsync(deg, 0, (size_t)N * 4, stream);

    cast_bf16<<<(n4 + 255) / 256, 256, 0, stream>>>(x, xb, n4);
    hist_kernel<<<nbE, 256, 0, stream>>>(dstp, deg, E);
    scan_a<<<nbN, 256, 0, stream>>>(deg, rowptr, bsums, N);
    scan_b<<<1, 512, 0, stream>>>(bsums, nbN);
    scan_c<<<nbN, 256, 0, stream>>>(deg, rowptr, cursor, bsums, N);
    scatter_kernel<<<nbE, 256, 0, stream>>>(srcp, dstp, cursor, bucket, E);

    // grid capped at 1024 (4 blocks/CU, 16 waves/CU): R3's concurrency regime;
    // R4's 32 waves/CU doubled L2 thrash.
    rgcn_fused<<<1024, 256, 0, stream>>>(xb, rowptr, bucket, W1, root1, b1, h1, N);
    rgcn_fused<<<1024, 256, 0, stream>>>(h1, rowptr, bucket, W2, root2, b2, h2, N);

    graph_bounds<<<1, 128, 0, stream>>>(batch, gstart, N);
    pool_kernel<<<64, 256, 0, stream>>>(h2, gstart, pooled);
    head_kernel<<<1, 256, 0, stream>>>(pooled, Wh, bh, Wc, bc, Wo, bo, out);
}

// Round 6
// 481.169 us; speedup vs baseline: 3.1273x; 1.6370x over previous
//
#include <hip/hip_runtime.h>
#include <hip/hip_bf16.h>

// FEAT=EMB=HID=64, VOCAB=32, N_GRAPHS=64. N,E from in_sizes.
// R6: transform-first. mean-agg commutes with the linear map, so:
//   xW = x @ W ; xRb = x @ root + b   (dense MFMA GEMM, M=N_nodes, K=64, N=128)
//   out[i] = relu( mean_{j in N(i)} xW[j] + xRb[i] )   (pure gather, no matvec)
// Tables bf16, ALL global accesses >= dword per lane (R4 lesson: sub-dword
// gathers cost ~16B/lane fetch granule; R5 verified dword gather = compulsory
// traffic only).

typedef __attribute__((ext_vector_type(8))) short short8;
typedef __attribute__((ext_vector_type(4))) float f32x4;

__device__ inline float bf2f(unsigned short h) {
    return __uint_as_float(((unsigned int)h) << 16);
}
__device__ inline float bflo(unsigned int u) { return __uint_as_float(u << 16); }
__device__ inline float bfhi(unsigned int u) { return __uint_as_float(u & 0xffff0000u); }
__device__ inline unsigned short f2bf(float f) {
    unsigned int u = __float_as_uint(f);
    u = (u + 0x7fffu + ((u >> 16) & 1u)) >> 16;  // RNE
    return (unsigned short)u;
}

// ---------------- cast x (fp32) -> bf16 table ----------------
__global__ __launch_bounds__(256) void cast_bf16(const float* __restrict__ x,
                                                 unsigned short* __restrict__ xb, int n4) {
    int i = blockIdx.x * 256 + threadIdx.x;
    if (i < n4) {
        const float4 v = ((const float4*)x)[i];
        ushort4 o;
        o.x = f2bf(v.x); o.y = f2bf(v.y); o.z = f2bf(v.z); o.w = f2bf(v.w);
        ((ushort4*)xb)[i] = o;
    }
}

// ---------------- CSR build ----------------

__global__ __launch_bounds__(256) void hist_kernel(const int* __restrict__ dst,
                                                   int* __restrict__ deg, int E) {
    int e = blockIdx.x * 256 + threadIdx.x;
    if (e < E) atomicAdd(&deg[dst[e]], 1);
}

__global__ __launch_bounds__(256) void scan_a(const int* __restrict__ deg,
                                              int* __restrict__ incl,
                                              int* __restrict__ bsums, int N) {
    __shared__ int tmp[256];
    int i = blockIdx.x * 256 + threadIdx.x;
    int v = (i < N) ? deg[i] : 0;
    tmp[threadIdx.x] = v;
    __syncthreads();
    for (int off = 1; off < 256; off <<= 1) {
        int t = (threadIdx.x >= off) ? tmp[threadIdx.x - off] : 0;
        __syncthreads();
        tmp[threadIdx.x] += t;
        __syncthreads();
    }
    if (i < N) incl[i] = tmp[threadIdx.x];
    if (threadIdx.x == 255) bsums[blockIdx.x] = tmp[255];
}

__global__ __launch_bounds__(512) void scan_b(int* __restrict__ bsums, int nb) {
    __shared__ int tmp[512];
    int t = threadIdx.x;
    int v = (t < nb) ? bsums[t] : 0;
    tmp[t] = v;
    __syncthreads();
    for (int off = 1; off < 512; off <<= 1) {
        int u = (t >= off) ? tmp[t - off] : 0;
        __syncthreads();
        tmp[t] += u;
        __syncthreads();
    }
    if (t < nb) bsums[t] = tmp[t] - v;  // exclusive
}

__global__ __launch_bounds__(256) void scan_c(const int* __restrict__ deg,
                                              int* __restrict__ rowptr,  // incl on entry
                                              int* __restrict__ cursor,
                                              const int* __restrict__ bsums, int N) {
    int i = blockIdx.x * 256 + threadIdx.x;
    if (i < N) {
        int d = deg[i];
        int excl = rowptr[i] - d + bsums[blockIdx.x];
        rowptr[i] = excl;
        cursor[i] = excl;
        if (i == N - 1) rowptr[N] = excl + d;
    }
}

__global__ __launch_bounds__(256) void scatter_kernel(const int* __restrict__ src,
                                                      const int* __restrict__ dst,
                                                      int* __restrict__ cursor,
                                                      int* __restrict__ bucket, int E) {
    int e = blockIdx.x * 256 + threadIdx.x;
    if (e < E) {
        int d = dst[e];
        int pos = atomicAdd(&cursor[d], 1);
        bucket[pos] = src[e];
    }
}

// ---------------- weight transpose prep ----------------
// Bt[n][k] (n=0..127, k=0..63), bf16: n<64 -> W[k][n], n>=64 -> R[k][n-64].
// blockIdx.x selects layer.
__global__ __launch_bounds__(256) void prep_bt(const float* __restrict__ W1,
                                               const float* __restrict__ R1,
                                               const float* __restrict__ W2,
                                               const float* __restrict__ R2,
                                               unsigned short* __restrict__ bt) {
    const float* W = blockIdx.x ? W2 : W1;
    const float* R = blockIdx.x ? R2 : R1;
    unsigned short* o = bt + (size_t)blockIdx.x * 8192;
    for (int idx = threadIdx.x; idx < 8192; idx += 256) {
        const int n = idx >> 6, k = idx & 63;
        const float v = (n < 64) ? W[k * 64 + n] : R[k * 64 + (n - 64)];
        o[idx] = f2bf(v);
    }
}

// ---------------- dense GEMM: y = x @ [W | R], bias folded into R half -----
// A-frag (16x16x32): A[m=lane&15][k=(lane>>4)*8+j]  [guide §3, m89-verified]
// D-frag: col=lane&15, row=(lane>>4)*4+reg
__global__ __launch_bounds__(256) void gemm_xwr(const unsigned short* __restrict__ xin,
                                                const unsigned short* __restrict__ bt,
                                                const float* __restrict__ bias,
                                                unsigned short* __restrict__ xw,
                                                unsigned short* __restrict__ xrb,
                                                int M) {
    const int lane = threadIdx.x & 63;
    const int q = lane >> 4;    // quad 0..3
    const int mm = lane & 15;

    // B-fragments, register-resident: 8 n-tiles x 2 k-chunks
    short8 bfrag[8][2];
#pragma unroll
    for (int t = 0; t < 8; ++t)
#pragma unroll
        for (int c = 0; c < 2; ++c)
            bfrag[t][c] = *(const short8*)&bt[(size_t)(t * 16 + mm) * 64 + c * 32 + q * 8];
    float bv[4];
#pragma unroll
    for (int tt = 0; tt < 4; ++tt) bv[tt] = bias[tt * 16 + mm];

    const int wid = threadIdx.x >> 6;
    const int gw = blockIdx.x * 4 + wid;
    const int nw = gridDim.x * 4;
    const int ntiles = M >> 4;

    for (int tile = gw; tile < ntiles; tile += nw) {
        const int row0 = tile << 4;
        const short8 a0 = *(const short8*)&xin[(size_t)(row0 + mm) * 64 + q * 8];
        const short8 a1 = *(const short8*)&xin[(size_t)(row0 + mm) * 64 + 32 + q * 8];
        f32x4 acc[8];
#pragma unroll
        for (int t = 0; t < 8; ++t) {
            acc[t] = (f32x4){0.f, 0.f, 0.f, 0.f};
            acc[t] = __builtin_amdgcn_mfma_f32_16x16x32_bf16(a0, bfrag[t][0], acc[t], 0, 0, 0);
            acc[t] = __builtin_amdgcn_mfma_f32_16x16x32_bf16(a1, bfrag[t][1], acc[t], 0, 0, 0);
        }
        // epilogue: pack bf16 pairs across (n, n+1) lanes, even lanes store dword
#pragma unroll
        for (int t = 0; t < 4; ++t) {
#pragma unroll
            for (int r = 0; r < 4; ++r) {
                const float v = acc[t][r];
                const float vn = __shfl_down(v, 1);
                if (!(mm & 1)) {
                    const unsigned int u = (unsigned int)f2bf(v) | ((unsigned int)f2bf(vn) << 16);
                    *(unsigned int*)&xw[(size_t)(row0 + q * 4 + r) * 64 + t * 16 + mm] = u;
                }
            }
        }
#pragma unroll
        for (int t = 4; t < 8; ++t) {
#pragma unroll
            for (int r = 0; r < 4; ++r) {
                const float v = acc[t][r] + bv[t - 4];
                const float vn = __shfl_down(v, 1);
                if (!(mm & 1)) {
                    const unsigned int u = (unsigned int)f2bf(v) | ((unsigned int)f2bf(vn) << 16);
                    *(unsigned int*)&xrb[(size_t)(row0 + q * 4 + r) * 64 + (t - 4) * 16 + mm] = u;
                }
            }
        }
    }
}

// ---------------- aggregate: out[i] = relu(mean_j xW[j] + xRb[i]) ----------
// One wave per node; bf16 row (128B) read as 32-lane dwords, 2 rows per
// instruction, 16-row unroll = 8 loads in flight. No LDS.
__global__ __launch_bounds__(256) void aggregate(const unsigned short* __restrict__ xw,
                                                 const unsigned short* __restrict__ xrb,
                                                 const int* __restrict__ rowptr,
                                                 const int* __restrict__ bucket,
                                                 unsigned short* __restrict__ outb,
                                                 int N) {
    const int lane = threadIdx.x & 63;
    const int half = lane >> 5;
    const int fl = lane & 31;  // feature-pair index (feats 2fl, 2fl+1)
    const int wid = threadIdx.x >> 6;
    const int gw = blockIdx.x * 4 + wid;
    const int nw = gridDim.x * 4;

    for (int i = gw; i < N; i += nw) {
        const int r0 = rowptr[i];
        const int dg = rowptr[i + 1] - r0;
        float lo0 = 0.f, lo1 = 0.f, hi0 = 0.f, hi1 = 0.f;
        for (int base = 0; base < dg; base += 64) {
            int m = dg - base;
            if (m > 64) m = 64;
            int s = (lane < m) ? bucket[r0 + base + lane] : 0;
            int j = 0;
            for (; j + 16 <= m; j += 16) {
                unsigned int u0, u1, u2, u3, u4, u5, u6, u7;
#define ROW2(uu, jj)                                                              \
    {                                                                             \
        const int ra_ = __shfl(s, (jj)), rb_ = __shfl(s, (jj) + 1);               \
        const int rr_ = half ? rb_ : ra_;                                         \
        uu = *(const unsigned int*)&xw[(size_t)rr_ * 64 + fl * 2];                \
    }
                ROW2(u0, j + 0) ROW2(u1, j + 2) ROW2(u2, j + 4) ROW2(u3, j + 6)
                ROW2(u4, j + 8) ROW2(u5, j + 10) ROW2(u6, j + 12) ROW2(u7, j + 14)
                lo0 += bflo(u0); hi0 += bfhi(u0);
                lo1 += bflo(u1); hi1 += bfhi(u1);
                lo0 += bflo(u2); hi0 += bfhi(u2);
                lo1 += bflo(u3); hi1 += bfhi(u3);
                lo0 += bflo(u4); hi0 += bfhi(u4);
                lo1 += bflo(u5); hi1 += bfhi(u5);
                lo0 += bflo(u6); hi0 += bfhi(u6);
                lo1 += bflo(u7); hi1 += bfhi(u7);
            }
            for (; j + 2 <= m; j += 2) {
                unsigned int u;
                ROW2(u, j)
                lo0 += bflo(u); hi0 += bfhi(u);
            }
            if (j < m) {
                const int ra = __shfl(s, j);
                const unsigned int u = *(const unsigned int*)&xw[(size_t)ra * 64 + fl * 2];
                const float w = half ? 0.f : 1.f;
                lo0 += w * bflo(u); hi0 += w * bfhi(u);
            }
#undef ROW2
        }
        float lo = lo0 + lo1, hi = hi0 + hi1;
        lo += __shfl_xor(lo, 32);
        hi += __shfl_xor(hi, 32);

        const float inv = 1.0f / (float)(dg > 0 ? dg : 1);
        const unsigned int ur = *(const unsigned int*)&xrb[(size_t)i * 64 + fl * 2];
        const float o0 = fmaxf(lo * inv + bflo(ur), 0.f);
        const float o1 = fmaxf(hi * inv + bfhi(ur), 0.f);
        if (half == 0) {
            const unsigned int u = (unsigned int)f2bf(o0) | ((unsigned int)f2bf(o1) << 16);
            *(unsigned int*)&outb[(size_t)i * 64 + fl * 2] = u;
        }
    }
}

// ---------------- Pooling (batch sorted): bounds + per-graph block sum ----------
__global__ __launch_bounds__(128) void graph_bounds(const int* __restrict__ batch,
                                                    int* __restrict__ gstart, int N) {
    int t = threadIdx.x;
    if (t > 64) return;
    if (t == 64) { gstart[64] = N; return; }
    int lo = 0, hi = N;
    while (lo < hi) {
        int mid = (lo + hi) >> 1;
        if (batch[mid] < t) lo = mid + 1; else hi = mid;
    }
    gstart[t] = lo;
}

__global__ __launch_bounds__(256) void pool_kernel(const unsigned short* __restrict__ h,
                                                   const int* __restrict__ gstart,
                                                   float* __restrict__ pooled) {
    __shared__ float red[16][64];
    const int gph = blockIdx.x;
    const int r0 = gstart[gph], r1 = gstart[gph + 1];
    const int f = threadIdx.x & 15;
    const int r = threadIdx.x >> 4;
    float4 acc = {0.f, 0.f, 0.f, 0.f};
    for (int row = r0 + r; row < r1; row += 16) {
        const ushort4 v = *(const ushort4*)&h[(size_t)row * 64 + f * 4];
        acc.x += bf2f(v.x); acc.y += bf2f(v.y);
        acc.z += bf2f(v.z); acc.w += bf2f(v.w);
    }
    red[r][f * 4 + 0] = acc.x; red[r][f * 4 + 1] = acc.y;
    red[r][f * 4 + 2] = acc.z; red[r][f * 4 + 3] = acc.w;
    __syncthreads();
    if (threadIdx.x < 64) {
        float s = 0.f;
        for (int j = 0; j < 16; ++j) s += red[j][threadIdx.x];
        const int cnt = r1 - r0;
        const float invc = 1.0f / (float)(cnt > 0 ? cnt : 1);
        pooled[gph * 64 + threadIdx.x] = s * invc;  // mean directly
    }
}

// ---------------- Heads ----------------
__global__ __launch_bounds__(256) void head_kernel(const float* __restrict__ pooled,
                                                   const float* __restrict__ Wh,
                                                   const float* __restrict__ bh,
                                                   const float* __restrict__ Wc,
                                                   const float* __restrict__ bc,
                                                   const float* __restrict__ Wo,
                                                   const float* __restrict__ bo,
                                                   float* __restrict__ out) {
    __shared__ float pm[4096];
    __shared__ float hid[4096];
    __shared__ float lg[2048];
    const int t = threadIdx.x;

    for (int idx = t; idx < 4096; idx += 256) pm[idx] = pooled[idx];
    __syncthreads();

    for (int idx = t; idx < 4096; idx += 256) {
        int g = idx >> 6, o = idx & 63;
        float ah = bh[o], ac = bc[o];
        for (int k = 0; k < 64; ++k) {
            float p = pm[(g << 6) + k];
            ah += p * Wh[k * 64 + o];
            ac += p * Wc[k * 64 + o];
        }
        hid[idx] = ah;
        out[2048 + idx] = ah;  // hidden
        out[6144 + idx] = ac;  // cell
    }
    __syncthreads();

    for (int idx = t; idx < 2048; idx += 256) {
        int g = idx >> 5, v = idx & 31;
        float a = bo[v];
        for (int k = 0; k < 64; ++k) a += hid[(g << 6) + k] * Wo[k * 32 + v];
        lg[idx] = a;
    }
    __syncthreads();

    if (t < 64) {
        float mx = -3.4e38f;
        for (int v = 0; v < 32; ++v) mx = fmaxf(mx, lg[(t << 5) + v]);
        float s = 0.f;
        for (int v = 0; v < 32; ++v) s += expf(lg[(t << 5) + v] - mx);
        float lse = mx + logf(s);
        for (int v = 0; v < 32; ++v) out[(t << 5) + v] = lg[(t << 5) + v] - lse;
    }
}

extern "C" void kernel_launch(void* const* d_in, const int* in_sizes, int n_in,
                              void* d_out, int out_size, void* d_ws, size_t ws_size,
                              hipStream_t stream) {
    const float* x = (const float*)d_in[0];
    const int* ei = (const int*)d_in[1];
    const int* batch = (const int*)d_in[2];
    const float* W1 = (const float*)d_in[3];
    const float* root1 = (const float*)d_in[4];
    const float* b1 = (const float*)d_in[5];
    const float* W2 = (const float*)d_in[6];
    const float* root2 = (const float*)d_in[7];
    const float* b2 = (const float*)d_in[8];
    const float* Wh = (const float*)d_in[9];
    const float* bh = (const float*)d_in[10];
    const float* Wc = (const float*)d_in[11];
    const float* bc = (const float*)d_in[12];
    const float* Wo = (const float*)d_in[13];
    const float* bo = (const float*)d_in[14];
    float* out = (float*)d_out;

    const int N = in_sizes[0] / 64;
    const int E = in_sizes[1] / 2;
    const int* srcp = ei;
    const int* dstp = ei + E;

    char* ws = (char*)d_ws;
    size_t off = 0;
    auto alloc = [&](size_t bytes) -> void* {
        void* p = ws + off;
        off += (bytes + 255) & ~(size_t)255;
        return p;
    };
    int* deg = (int*)alloc((size_t)N * 4);
    int* rowptr = (int*)alloc((size_t)(N + 1) * 4);
    int* cursor = (int*)alloc((size_t)N * 4);
    int* bsums = (int*)alloc(512 * 4);
    int* bucket = (int*)alloc((size_t)E * 4);
    unsigned short* xb = (unsigned short*)alloc((size_t)N * 64 * 2);  // also reused as h2
    unsigned short* h1 = (unsigned short*)alloc((size_t)N * 64 * 2);
    unsigned short* xw = (unsigned short*)alloc((size_t)N * 64 * 2);
    unsigned short* xrb = (unsigned short*)alloc((size_t)N * 64 * 2);
    unsigned short* bt = (unsigned short*)alloc(2 * 8192 * 2);
    float* pooled = (float*)alloc(4096 * 4);
    int* gstart = (int*)alloc(65 * 4);
    unsigned short* h2 = xb;  // xb dead after gemm layer 1

    const int nbN = (N + 255) / 256;
    const int nbE = (E + 255) / 256;
    const int n4 = N * 16;

    hipMemsetAsync(deg, 0, (size_t)N * 4, stream);

    cast_bf16<<<(n4 + 255) / 256, 256, 0, stream>>>(x, xb, n4);
    hist_kernel<<<nbE, 256, 0, stream>>>(dstp, deg, E);
    scan_a<<<nbN, 256, 0, stream>>>(deg, rowptr, bsums, N);
    scan_b<<<1, 512, 0, stream>>>(bsums, nbN);
    scan_c<<<nbN, 256, 0, stream>>>(deg, rowptr, cursor, bsums, N);
    scatter_kernel<<<nbE, 256, 0, stream>>>(srcp, dstp, cursor, bucket, E);
    prep_bt<<<2, 256, 0, stream>>>(W1, root1, W2, root2, bt);

    // layer 1
    gemm_xwr<<<1024, 256, 0, stream>>>(xb, bt, b1, xw, xrb, N);
    aggregate<<<2048, 256, 0, stream>>>(xw, xrb, rowptr, bucket, h1, N);
    // layer 2
    gemm_xwr<<<1024, 256, 0, stream>>>(h1, bt + 8192, b2, xw, xrb, N);
    aggregate<<<2048, 256, 0, stream>>>(xw, xrb, rowptr, bucket, h2, N);

    graph_bounds<<<1, 128, 0, stream>>>(batch, gstart, N);
    pool_kernel<<<64, 256, 0, stream>>>(h2, gstart, pooled);
    head_kernel<<<1, 256, 0, stream>>>(pooled, Wh, bh, Wc, bc, Wo, bo, out);
}

// Round 7
// 327.539 us; speedup vs baseline: 4.5941x; 1.4690x over previous
//
#include <hip/hip_runtime.h>
#include <hip/hip_bf16.h>

// FEAT=EMB=HID=64, VOCAB=32, N_GRAPHS=64. N,E from in_sizes.
// R6: transform-first (xW = x@W once, then pure gather-mean).
// R7: CSR build rebuilt as two-level binning sort — R6's scatter_kernel did
// 1.6M random dword writes -> ~105MB HBM write (cross-XCD line dirtying).
// Binning keeps every global write coalesced (~1x amplification).

typedef __attribute__((ext_vector_type(8))) short short8;
typedef __attribute__((ext_vector_type(4))) float f32x4;

#define RB 9            // region bits: 512 nodes per coarse bin
#define MAXBINS 256     // supports N <= 131072
#define CAP 12288       // per-bin region capacity (mean ~8163 at E=1.6M, >40 sigma)
#define CHUNK 8192      // edges per bin_edges block

__device__ inline float bf2f(unsigned short h) {
    return __uint_as_float(((unsigned int)h) << 16);
}
__device__ inline float bflo(unsigned int u) { return __uint_as_float(u << 16); }
__device__ inline float bfhi(unsigned int u) { return __uint_as_float(u & 0xffff0000u); }
__device__ inline unsigned short f2bf(float f) {
    unsigned int u = __float_as_uint(f);
    u = (u + 0x7fffu + ((u >> 16) & 1u)) >> 16;  // RNE
    return (unsigned short)u;
}

// ---------------- cast x (fp32) -> bf16 table ----------------
__global__ __launch_bounds__(256) void cast_bf16(const float* __restrict__ x,
                                                 unsigned short* __restrict__ xb, int n4) {
    int i = blockIdx.x * 256 + threadIdx.x;
    if (i < n4) {
        const float4 v = ((const float4*)x)[i];
        ushort4 o;
        o.x = f2bf(v.x); o.y = f2bf(v.y); o.z = f2bf(v.z); o.w = f2bf(v.w);
        ((ushort4*)xb)[i] = o;
    }
}

// ---------------- CSR build: two-level binning ----------------

__global__ __launch_bounds__(256) void init_gcur(int* __restrict__ gcur) {
    gcur[threadIdx.x] = threadIdx.x * CAP;
}

// Phase 1: bin edges into coarse per-bin regions. Entry = src | (dst&511)<<17.
__global__ __launch_bounds__(256) void bin_edges(const int* __restrict__ src,
                                                 const int* __restrict__ dst,
                                                 unsigned int* __restrict__ coarse,
                                                 int* __restrict__ gcur,
                                                 int E, int BINS) {
    __shared__ int cnt[MAXBINS];
    __shared__ int incl[MAXBINS];
    __shared__ int bstart[MAXBINS];
    __shared__ int bcur[MAXBINS];
    __shared__ int gbase[MAXBINS];
    __shared__ unsigned int stage[CHUNK];
    __shared__ unsigned char binOf[CHUNK];

    const int tid = threadIdx.x;
    const int chunk0 = blockIdx.x * CHUNK;
    int myS[32], myD[32];
#pragma unroll
    for (int k = 0; k < 32; ++k) {
        const int idx = chunk0 + k * 256 + tid;
        if (idx < E) { myS[k] = src[idx]; myD[k] = dst[idx]; }
        else myD[k] = -1;
    }
    cnt[tid] = 0;
    __syncthreads();
#pragma unroll
    for (int k = 0; k < 32; ++k)
        if (myD[k] >= 0) atomicAdd(&cnt[myD[k] >> RB], 1);
    __syncthreads();
    // inclusive scan of cnt -> incl (Hillis-Steele, proven pattern)
    incl[tid] = cnt[tid];
    __syncthreads();
    for (int off = 1; off < 256; off <<= 1) {
        int t = (tid >= off) ? incl[tid - off] : 0;
        __syncthreads();
        incl[tid] += t;
        __syncthreads();
    }
    bstart[tid] = incl[tid] - cnt[tid];
    bcur[tid] = incl[tid] - cnt[tid];
    __syncthreads();
    // place into LDS stage, bin-sorted
#pragma unroll
    for (int k = 0; k < 32; ++k) {
        if (myD[k] >= 0) {
            const int b = myD[k] >> RB;
            const int pos = atomicAdd(&bcur[b], 1);
            stage[pos] = (unsigned int)myS[k] | ((unsigned int)(myD[k] & ((1 << RB) - 1)) << 17);
            binOf[pos] = (unsigned char)b;
        }
    }
    __syncthreads();
    // reserve global space per bin
    if (tid < BINS && cnt[tid] > 0) gbase[tid] = atomicAdd(&gcur[tid], cnt[tid]);
    __syncthreads();
    // flush: consecutive idx are bin-runs -> coalesced global writes
    int total = E - chunk0;
    if (total > CHUNK) total = CHUNK;
    for (int idx = tid; idx < total; idx += 256) {
        const int b = binOf[idx];
        coarse[gbase[b] + (idx - bstart[b])] = stage[idx];
    }
}

// Phase 1.5: exclusive scan of bin counts -> binbase
__global__ __launch_bounds__(256) void scan_bins(const int* __restrict__ gcur,
                                                 int* __restrict__ binbase, int BINS) {
    __shared__ int tmp[MAXBINS];
    const int t = threadIdx.x;
    const int c = (t < BINS) ? (gcur[t] - t * CAP) : 0;
    tmp[t] = c;
    __syncthreads();
    for (int off = 1; off < 256; off <<= 1) {
        int u = (t >= off) ? tmp[t - off] : 0;
        __syncthreads();
        tmp[t] += u;
        __syncthreads();
    }
    if (t < BINS) binbase[t] = tmp[t] - c;  // exclusive
}

// Phase 2: one block per bin -> exact CSR (bucket of src ids + rowptr), all
// global writes coalesced.
__global__ __launch_bounds__(256) void finalize_csr(const unsigned int* __restrict__ coarse,
                                                    const int* __restrict__ gcur,
                                                    const int* __restrict__ binbase,
                                                    int* __restrict__ bucket,
                                                    int* __restrict__ rowptr,
                                                    int N, int E, int BINS) {
    __shared__ int ncnt[512];
    __shared__ int nexcl[512];
    __shared__ int ncur[512];
    __shared__ int s2[256];
    __shared__ unsigned int st[CAP];

    const int b = blockIdx.x;
    const int tid = threadIdx.x;
    const int cb = gcur[b] - b * CAP;
    const int base = binbase[b];
    const unsigned int* reg = coarse + (size_t)b * CAP;
    const int node0 = b << RB;
    int nloc = N - node0;
    if (nloc > 512) nloc = 512;

    ncnt[tid] = 0; ncnt[tid + 256] = 0;
    __syncthreads();
    for (int idx = tid; idx < cb; idx += 256)
        atomicAdd(&ncnt[reg[idx] >> 17], 1);
    __syncthreads();
    // exclusive scan over 512 via pair-reduction + 256-scan
    s2[tid] = ncnt[2 * tid] + ncnt[2 * tid + 1];
    __syncthreads();
    for (int off = 1; off < 256; off <<= 1) {
        int t = (tid >= off) ? s2[tid - off] : 0;
        __syncthreads();
        s2[tid] += t;
        __syncthreads();
    }
    const int pairExcl = s2[tid] - (ncnt[2 * tid] + ncnt[2 * tid + 1]);
    nexcl[2 * tid] = pairExcl;
    nexcl[2 * tid + 1] = pairExcl + ncnt[2 * tid];
    ncur[2 * tid] = nexcl[2 * tid];
    ncur[2 * tid + 1] = nexcl[2 * tid + 1];
    __syncthreads();
    // rowptr (coalesced)
    for (int i = tid; i < nloc; i += 256) rowptr[node0 + i] = base + nexcl[i];
    if (b == BINS - 1 && tid == 0) rowptr[N] = E;
    // place src ids at exact CSR positions in LDS
    for (int idx = tid; idx < cb; idx += 256) {
        const unsigned int e = reg[idx];
        const int p = atomicAdd(&ncur[e >> 17], 1);
        st[p] = e & 0x1FFFFu;
    }
    __syncthreads();
    // flush (fully coalesced)
    for (int idx = tid; idx < cb; idx += 256) bucket[base + idx] = (int)st[idx];
}

// ---------------- weight transpose prep ----------------
__global__ __launch_bounds__(256) void prep_bt(const float* __restrict__ W1,
                                               const float* __restrict__ R1,
                                               const float* __restrict__ W2,
                                               const float* __restrict__ R2,
                                               unsigned short* __restrict__ bt) {
    const float* W = blockIdx.x ? W2 : W1;
    const float* R = blockIdx.x ? R2 : R1;
    unsigned short* o = bt + (size_t)blockIdx.x * 8192;
    for (int idx = threadIdx.x; idx < 8192; idx += 256) {
        const int n = idx >> 6, k = idx & 63;
        const float v = (n < 64) ? W[k * 64 + n] : R[k * 64 + (n - 64)];
        o[idx] = f2bf(v);
    }
}

// ---------------- dense GEMM: y = x @ [W | R], bias folded into R half -----
__global__ __launch_bounds__(256) void gemm_xwr(const unsigned short* __restrict__ xin,
                                                const unsigned short* __restrict__ bt,
                                                const float* __restrict__ bias,
                                                unsigned short* __restrict__ xw,
                                                unsigned short* __restrict__ xrb,
                                                int M) {
    const int lane = threadIdx.x & 63;
    const int q = lane >> 4;
    const int mm = lane & 15;

    short8 bfrag[8][2];
#pragma unroll
    for (int t = 0; t < 8; ++t)
#pragma unroll
        for (int c = 0; c < 2; ++c)
            bfrag[t][c] = *(const short8*)&bt[(size_t)(t * 16 + mm) * 64 + c * 32 + q * 8];
    float bv[4];
#pragma unroll
    for (int tt = 0; tt < 4; ++tt) bv[tt] = bias[tt * 16 + mm];

    const int wid = threadIdx.x >> 6;
    const int gw = blockIdx.x * 4 + wid;
    const int nw = gridDim.x * 4;
    const int ntiles = M >> 4;

    for (int tile = gw; tile < ntiles; tile += nw) {
        const int row0 = tile << 4;
        const short8 a0 = *(const short8*)&xin[(size_t)(row0 + mm) * 64 + q * 8];
        const short8 a1 = *(const short8*)&xin[(size_t)(row0 + mm) * 64 + 32 + q * 8];
        f32x4 acc[8];
#pragma unroll
        for (int t = 0; t < 8; ++t) {
            acc[t] = (f32x4){0.f, 0.f, 0.f, 0.f};
            acc[t] = __builtin_amdgcn_mfma_f32_16x16x32_bf16(a0, bfrag[t][0], acc[t], 0, 0, 0);
            acc[t] = __builtin_amdgcn_mfma_f32_16x16x32_bf16(a1, bfrag[t][1], acc[t], 0, 0, 0);
        }
#pragma unroll
        for (int t = 0; t < 4; ++t) {
#pragma unroll
            for (int r = 0; r < 4; ++r) {
                const float v = acc[t][r];
                const float vn = __shfl_down(v, 1);
                if (!(mm & 1)) {
                    const unsigned int u = (unsigned int)f2bf(v) | ((unsigned int)f2bf(vn) << 16);
                    *(unsigned int*)&xw[(size_t)(row0 + q * 4 + r) * 64 + t * 16 + mm] = u;
                }
            }
        }
#pragma unroll
        for (int t = 4; t < 8; ++t) {
#pragma unroll
            for (int r = 0; r < 4; ++r) {
                const float v = acc[t][r] + bv[t - 4];
                const float vn = __shfl_down(v, 1);
                if (!(mm & 1)) {
                    const unsigned int u = (unsigned int)f2bf(v) | ((unsigned int)f2bf(vn) << 16);
                    *(unsigned int*)&xrb[(size_t)(row0 + q * 4 + r) * 64 + (t - 4) * 16 + mm] = u;
                }
            }
        }
    }
}

// ---------------- aggregate: out[i] = relu(mean_j xW[j] + xRb[i]) ----------
__global__ __launch_bounds__(256) void aggregate(const unsigned short* __restrict__ xw,
                                                 const unsigned short* __restrict__ xrb,
                                                 const int* __restrict__ rowptr,
                                                 const int* __restrict__ bucket,
                                                 unsigned short* __restrict__ outb,
                                                 int N) {
    const int lane = threadIdx.x & 63;
    const int half = lane >> 5;
    const int fl = lane & 31;
    const int wid = threadIdx.x >> 6;
    const int gw = blockIdx.x * 4 + wid;
    const int nw = gridDim.x * 4;

    for (int i = gw; i < N; i += nw) {
        const int r0 = rowptr[i];
        const int dg = rowptr[i + 1] - r0;
        float lo0 = 0.f, lo1 = 0.f, hi0 = 0.f, hi1 = 0.f;
        for (int base = 0; base < dg; base += 64) {
            int m = dg - base;
            if (m > 64) m = 64;
            int s = (lane < m) ? bucket[r0 + base + lane] : 0;
            int j = 0;
            for (; j + 16 <= m; j += 16) {
                unsigned int u0, u1, u2, u3, u4, u5, u6, u7;
#define ROW2(uu, jj)                                                              \
    {                                                                             \
        const int ra_ = __shfl(s, (jj)), rb_ = __shfl(s, (jj) + 1);               \
        const int rr_ = half ? rb_ : ra_;                                         \
        uu = *(const unsigned int*)&xw[(size_t)rr_ * 64 + fl * 2];                \
    }
                ROW2(u0, j + 0) ROW2(u1, j + 2) ROW2(u2, j + 4) ROW2(u3, j + 6)
                ROW2(u4, j + 8) ROW2(u5, j + 10) ROW2(u6, j + 12) ROW2(u7, j + 14)
                lo0 += bflo(u0); hi0 += bfhi(u0);
                lo1 += bflo(u1); hi1 += bfhi(u1);
                lo0 += bflo(u2); hi0 += bfhi(u2);
                lo1 += bflo(u3); hi1 += bfhi(u3);
                lo0 += bflo(u4); hi0 += bfhi(u4);
                lo1 += bflo(u5); hi1 += bfhi(u5);
                lo0 += bflo(u6); hi0 += bfhi(u6);
                lo1 += bflo(u7); hi1 += bfhi(u7);
            }
            for (; j + 2 <= m; j += 2) {
                unsigned int u;
                ROW2(u, j)
                lo0 += bflo(u); hi0 += bfhi(u);
            }
            if (j < m) {
                const int ra = __shfl(s, j);
                const unsigned int u = *(const unsigned int*)&xw[(size_t)ra * 64 + fl * 2];
                const float w = half ? 0.f : 1.f;
                lo0 += w * bflo(u); hi0 += w * bfhi(u);
            }
#undef ROW2
        }
        float lo = lo0 + lo1, hi = hi0 + hi1;
        lo += __shfl_xor(lo, 32);
        hi += __shfl_xor(hi, 32);

        const float inv = 1.0f / (float)(dg > 0 ? dg : 1);
        const unsigned int ur = *(const unsigned int*)&xrb[(size_t)i * 64 + fl * 2];
        const float o0 = fmaxf(lo * inv + bflo(ur), 0.f);
        const float o1 = fmaxf(hi * inv + bfhi(ur), 0.f);
        if (half == 0) {
            const unsigned int u = (unsigned int)f2bf(o0) | ((unsigned int)f2bf(o1) << 16);
            *(unsigned int*)&outb[(size_t)i * 64 + fl * 2] = u;
        }
    }
}

// ---------------- Pooling (batch sorted): bounds + per-graph block sum ----------
__global__ __launch_bounds__(128) void graph_bounds(const int* __restrict__ batch,
                                                    int* __restrict__ gstart, int N) {
    int t = threadIdx.x;
    if (t > 64) return;
    if (t == 64) { gstart[64] = N; return; }
    int lo = 0, hi = N;
    while (lo < hi) {
        int mid = (lo + hi) >> 1;
        if (batch[mid] < t) lo = mid + 1; else hi = mid;
    }
    gstart[t] = lo;
}

__global__ __launch_bounds__(256) void pool_kernel(const unsigned short* __restrict__ h,
                                                   const int* __restrict__ gstart,
                                                   float* __restrict__ pooled) {
    __shared__ float red[16][64];
    const int gph = blockIdx.x;
    const int r0 = gstart[gph], r1 = gstart[gph + 1];
    const int f = threadIdx.x & 15;
    const int r = threadIdx.x >> 4;
    float4 acc = {0.f, 0.f, 0.f, 0.f};
    for (int row = r0 + r; row < r1; row += 16) {
        const ushort4 v = *(const ushort4*)&h[(size_t)row * 64 + f * 4];
        acc.x += bf2f(v.x); acc.y += bf2f(v.y);
        acc.z += bf2f(v.z); acc.w += bf2f(v.w);
    }
    red[r][f * 4 + 0] = acc.x; red[r][f * 4 + 1] = acc.y;
    red[r][f * 4 + 2] = acc.z; red[r][f * 4 + 3] = acc.w;
    __syncthreads();
    if (threadIdx.x < 64) {
        float s = 0.f;
        for (int j = 0; j < 16; ++j) s += red[j][threadIdx.x];
        const int cnt = r1 - r0;
        const float invc = 1.0f / (float)(cnt > 0 ? cnt : 1);
        pooled[gph * 64 + threadIdx.x] = s * invc;
    }
}

// ---------------- Heads ----------------
__global__ __launch_bounds__(256) void head_kernel(const float* __restrict__ pooled,
                                                   const float* __restrict__ Wh,
                                                   const float* __restrict__ bh,
                                                   const float* __restrict__ Wc,
                                                   const float* __restrict__ bc,
                                                   const float* __restrict__ Wo,
                                                   const float* __restrict__ bo,
                                                   float* __restrict__ out) {
    __shared__ float pm[4096];
    __shared__ float hid[4096];
    __shared__ float lg[2048];
    const int t = threadIdx.x;

    for (int idx = t; idx < 4096; idx += 256) pm[idx] = pooled[idx];
    __syncthreads();

    for (int idx = t; idx < 4096; idx += 256) {
        int g = idx >> 6, o = idx & 63;
        float ah = bh[o], ac = bc[o];
        for (int k = 0; k < 64; ++k) {
            float p = pm[(g << 6) + k];
            ah += p * Wh[k * 64 + o];
            ac += p * Wc[k * 64 + o];
        }
        hid[idx] = ah;
        out[2048 + idx] = ah;
        out[6144 + idx] = ac;
    }
    __syncthreads();

    for (int idx = t; idx < 2048; idx += 256) {
        int g = idx >> 5, v = idx & 31;
        float a = bo[v];
        for (int k = 0; k < 64; ++k) a += hid[(g << 6) + k] * Wo[k * 32 + v];
        lg[idx] = a;
    }
    __syncthreads();

    if (t < 64) {
        float mx = -3.4e38f;
        for (int v = 0; v < 32; ++v) mx = fmaxf(mx, lg[(t << 5) + v]);
        float s = 0.f;
        for (int v = 0; v < 32; ++v) s += expf(lg[(t << 5) + v] - mx);
        float lse = mx + logf(s);
        for (int v = 0; v < 32; ++v) out[(t << 5) + v] = lg[(t << 5) + v] - lse;
    }
}

extern "C" void kernel_launch(void* const* d_in, const int* in_sizes, int n_in,
                              void* d_out, int out_size, void* d_ws, size_t ws_size,
                              hipStream_t stream) {
    const float* x = (const float*)d_in[0];
    const int* ei = (const int*)d_in[1];
    const int* batch = (const int*)d_in[2];
    const float* W1 = (const float*)d_in[3];
    const float* root1 = (const float*)d_in[4];
    const float* b1 = (const float*)d_in[5];
    const float* W2 = (const float*)d_in[6];
    const float* root2 = (const float*)d_in[7];
    const float* b2 = (const float*)d_in[8];
    const float* Wh = (const float*)d_in[9];
    const float* bh = (const float*)d_in[10];
    const float* Wc = (const float*)d_in[11];
    const float* bc = (const float*)d_in[12];
    const float* Wo = (const float*)d_in[13];
    const float* bo = (const float*)d_in[14];
    float* out = (float*)d_out;

    const int N = in_sizes[0] / 64;
    const int E = in_sizes[1] / 2;
    const int* srcp = ei;
    const int* dstp = ei + E;
    const int BINS = (N + (1 << RB) - 1) >> RB;

    char* ws = (char*)d_ws;
    size_t off = 0;
    auto alloc = [&](size_t bytes) -> void* {
        void* p = ws + off;
        off += (bytes + 255) & ~(size_t)255;
        return p;
    };
    int* rowptr = (int*)alloc((size_t)(N + 1) * 4);
    int* bucket = (int*)alloc((size_t)E * 4);
    unsigned short* xb = (unsigned short*)alloc((size_t)N * 64 * 2);  // reused as h2
    unsigned short* h1 = (unsigned short*)alloc((size_t)N * 64 * 2);
    // xw shares space with coarse (coarse dead before gemm1 writes xw)
    size_t xw_bytes = (size_t)N * 64 * 2;
    size_t coarse_bytes = (size_t)BINS * CAP * 4;
    unsigned short* xw = (unsigned short*)alloc(xw_bytes > coarse_bytes ? xw_bytes : coarse_bytes);
    unsigned int* coarse = (unsigned int*)xw;
    unsigned short* xrb = (unsigned short*)alloc((size_t)N * 64 * 2);
    unsigned short* bt = (unsigned short*)alloc(2 * 8192 * 2);
    float* pooled = (float*)alloc(4096 * 4);
    int* gstart = (int*)alloc(65 * 4);
    int* gcur = (int*)alloc(MAXBINS * 4);
    int* binbase = (int*)alloc(MAXBINS * 4);
    unsigned short* h2 = xb;

    const int n4 = N * 16;
    const int nbBin = (E + CHUNK - 1) / CHUNK;

    // CSR build (binning) — coarse uses xw's slot, finished before gemm1
    init_gcur<<<1, 256, 0, stream>>>(gcur);
    bin_edges<<<nbBin, 256, 0, stream>>>(srcp, dstp, coarse, gcur, E, BINS);
    scan_bins<<<1, 256, 0, stream>>>(gcur, binbase, BINS);
    finalize_csr<<<BINS, 256, 0, stream>>>(coarse, gcur, binbase, bucket, rowptr, N, E, BINS);

    cast_bf16<<<(n4 + 255) / 256, 256, 0, stream>>>(x, xb, n4);
    prep_bt<<<2, 256, 0, stream>>>(W1, root1, W2, root2, bt);

    // layer 1
    gemm_xwr<<<1024, 256, 0, stream>>>(xb, bt, b1, xw, xrb, N);
    aggregate<<<2048, 256, 0, stream>>>(xw, xrb, rowptr, bucket, h1, N);
    // layer 2
    gemm_xwr<<<1024, 256, 0, stream>>>(h1, bt + 8192, b2, xw, xrb, N);
    aggregate<<<2048, 256, 0, stream>>>(xw, xrb, rowptr, bucket, h2, N);

    graph_bounds<<<1, 128, 0, stream>>>(batch, gstart, N);
    pool_kernel<<<64, 256, 0, stream>>>(h2, gstart, pooled);
    head_kernel<<<1, 256, 0, stream>>>(pooled, Wh, bh, Wc, bc, Wo, bo, out);
}

// Round 8
// 311.094 us; speedup vs baseline: 4.8369x; 1.0529x over previous
//
#include <hip/hip_runtime.h>
#include <hip/hip_bf16.h>

// FEAT=EMB=HID=64, VOCAB=32, N_GRAPHS=64. N,E from in_sizes.
// R6: transform-first (xW = x@W once, then pure gather-mean).
// R7: CSR via two-level binning (coalesced writes only).
// R8: aggregate uses an ALWAYS-RUN masked 16-row unroll — R7's remainder
// loop had 1 load in flight and dominated latency for deg<16 nodes (half of
// all nodes at Poisson(16)). Also fused/merged 4 small dispatches.

typedef __attribute__((ext_vector_type(8))) short short8;
typedef __attribute__((ext_vector_type(4))) float f32x4;

#define RB 9            // region bits: 512 nodes per coarse bin
#define MAXBINS 256     // supports N <= 131072
#define CAP 12288       // per-bin region capacity (mean ~8163 at E=1.6M)
#define CHUNK 8192      // edges per bin_edges block

__device__ inline float bf2f(unsigned short h) {
    return __uint_as_float(((unsigned int)h) << 16);
}
__device__ inline float bflo(unsigned int u) { return __uint_as_float(u << 16); }
__device__ inline float bfhi(unsigned int u) { return __uint_as_float(u & 0xffff0000u); }
__device__ inline unsigned short f2bf(float f) {
    unsigned int u = __float_as_uint(f);
    u = (u + 0x7fffu + ((u >> 16) & 1u)) >> 16;  // RNE
    return (unsigned short)u;
}

// ---------------- fused: cast x -> bf16 table + weight transpose prep -------
// blockIdx 0,1: build Bt for layer 1,2. blockIdx >=2: cast chunk.
__global__ __launch_bounds__(256) void prep_all(const float* __restrict__ x,
                                                unsigned short* __restrict__ xb, int n4,
                                                const float* __restrict__ W1,
                                                const float* __restrict__ R1,
                                                const float* __restrict__ W2,
                                                const float* __restrict__ R2,
                                                unsigned short* __restrict__ bt) {
    if (blockIdx.x < 2) {
        const float* W = blockIdx.x ? W2 : W1;
        const float* R = blockIdx.x ? R2 : R1;
        unsigned short* o = bt + (size_t)blockIdx.x * 8192;
        for (int idx = threadIdx.x; idx < 8192; idx += 256) {
            const int n = idx >> 6, k = idx & 63;
            const float v = (n < 64) ? W[k * 64 + n] : R[k * 64 + (n - 64)];
            o[idx] = f2bf(v);
        }
        return;
    }
    const int i = (blockIdx.x - 2) * 256 + threadIdx.x;
    if (i < n4) {
        const float4 v = ((const float4*)x)[i];
        ushort4 o;
        o.x = f2bf(v.x); o.y = f2bf(v.y); o.z = f2bf(v.z); o.w = f2bf(v.w);
        ((ushort4*)xb)[i] = o;
    }
}

// ---------------- CSR build: two-level binning ----------------
// gcur is pre-zeroed by hipMemsetAsync; holds per-bin counts after phase 1.

__global__ __launch_bounds__(256) void bin_edges(const int* __restrict__ src,
                                                 const int* __restrict__ dst,
                                                 unsigned int* __restrict__ coarse,
                                                 int* __restrict__ gcur,
                                                 int E, int BINS) {
    __shared__ int cnt[MAXBINS];
    __shared__ int incl[MAXBINS];
    __shared__ int bstart[MAXBINS];
    __shared__ int bcur[MAXBINS];
    __shared__ int gbase[MAXBINS];
    __shared__ unsigned int stage[CHUNK];
    __shared__ unsigned char binOf[CHUNK];

    const int tid = threadIdx.x;
    const int chunk0 = blockIdx.x * CHUNK;
    int myS[32], myD[32];
#pragma unroll
    for (int k = 0; k < 32; ++k) {
        const int idx = chunk0 + k * 256 + tid;
        if (idx < E) { myS[k] = src[idx]; myD[k] = dst[idx]; }
        else myD[k] = -1;
    }
    cnt[tid] = 0;
    __syncthreads();
#pragma unroll
    for (int k = 0; k < 32; ++k)
        if (myD[k] >= 0) atomicAdd(&cnt[myD[k] >> RB], 1);
    __syncthreads();
    incl[tid] = cnt[tid];
    __syncthreads();
    for (int off = 1; off < 256; off <<= 1) {
        int t = (tid >= off) ? incl[tid - off] : 0;
        __syncthreads();
        incl[tid] += t;
        __syncthreads();
    }
    bstart[tid] = incl[tid] - cnt[tid];
    bcur[tid] = incl[tid] - cnt[tid];
    __syncthreads();
#pragma unroll
    for (int k = 0; k < 32; ++k) {
        if (myD[k] >= 0) {
            const int b = myD[k] >> RB;
            const int pos = atomicAdd(&bcur[b], 1);
            stage[pos] = (unsigned int)myS[k] | ((unsigned int)(myD[k] & ((1 << RB) - 1)) << 17);
            binOf[pos] = (unsigned char)b;
        }
    }
    __syncthreads();
    if (tid < BINS && cnt[tid] > 0)
        gbase[tid] = tid * CAP + atomicAdd(&gcur[tid], cnt[tid]);
    __syncthreads();
    int total = E - chunk0;
    if (total > CHUNK) total = CHUNK;
    for (int idx = tid; idx < total; idx += 256) {
        const int b = binOf[idx];
        coarse[gbase[b] + (idx - bstart[b])] = stage[idx];
    }
}

// Phase 2: one block per bin -> exact CSR; computes its own base by scanning
// gcur (256 values) in LDS.
__global__ __launch_bounds__(256) void finalize_csr(const unsigned int* __restrict__ coarse,
                                                    const int* __restrict__ gcur,
                                                    int* __restrict__ bucket,
                                                    int* __restrict__ rowptr,
                                                    int N, int E, int BINS) {
    __shared__ int ncnt[512];
    __shared__ int nexcl[512];
    __shared__ int ncur[512];
    __shared__ int s2[256];
    __shared__ int cnts[256];
    __shared__ unsigned int st[CAP];
    __shared__ int sbase;

    const int b = blockIdx.x;
    const int tid = threadIdx.x;

    // compute binbase[b] = exclusive prefix of gcur at b
    const int c = (tid < BINS) ? gcur[tid] : 0;
    cnts[tid] = c;
    s2[tid] = c;
    __syncthreads();
    for (int off = 1; off < 256; off <<= 1) {
        int t = (tid >= off) ? s2[tid - off] : 0;
        __syncthreads();
        s2[tid] += t;
        __syncthreads();
    }
    if (tid == 0) sbase = s2[b] - cnts[b];
    ncnt[tid] = 0; ncnt[tid + 256] = 0;
    __syncthreads();

    const int cb = cnts[b];
    const int base = sbase;
    const unsigned int* reg = coarse + (size_t)b * CAP;
    const int node0 = b << RB;
    int nloc = N - node0;
    if (nloc > 512) nloc = 512;

    for (int idx = tid; idx < cb; idx += 256)
        atomicAdd(&ncnt[reg[idx] >> 17], 1);
    __syncthreads();
    s2[tid] = ncnt[2 * tid] + ncnt[2 * tid + 1];
    __syncthreads();
    for (int off = 1; off < 256; off <<= 1) {
        int t = (tid >= off) ? s2[tid - off] : 0;
        __syncthreads();
        s2[tid] += t;
        __syncthreads();
    }
    const int pairExcl = s2[tid] - (ncnt[2 * tid] + ncnt[2 * tid + 1]);
    nexcl[2 * tid] = pairExcl;
    nexcl[2 * tid + 1] = pairExcl + ncnt[2 * tid];
    ncur[2 * tid] = nexcl[2 * tid];
    ncur[2 * tid + 1] = nexcl[2 * tid + 1];
    __syncthreads();
    for (int i = tid; i < nloc; i += 256) rowptr[node0 + i] = base + nexcl[i];
    if (b == BINS - 1 && tid == 0) rowptr[N] = E;
    for (int idx = tid; idx < cb; idx += 256) {
        const unsigned int e = reg[idx];
        const int p = atomicAdd(&ncur[e >> 17], 1);
        st[p] = e & 0x1FFFFu;
    }
    __syncthreads();
    for (int idx = tid; idx < cb; idx += 256) bucket[base + idx] = (int)st[idx];
}

// ---------------- dense GEMM: y = x @ [W | R], bias folded into R half -----
__global__ __launch_bounds__(256) void gemm_xwr(const unsigned short* __restrict__ xin,
                                                const unsigned short* __restrict__ bt,
                                                const float* __restrict__ bias,
                                                unsigned short* __restrict__ xw,
                                                unsigned short* __restrict__ xrb,
                                                int M) {
    const int lane = threadIdx.x & 63;
    const int q = lane >> 4;
    const int mm = lane & 15;

    short8 bfrag[8][2];
#pragma unroll
    for (int t = 0; t < 8; ++t)
#pragma unroll
        for (int c = 0; c < 2; ++c)
            bfrag[t][c] = *(const short8*)&bt[(size_t)(t * 16 + mm) * 64 + c * 32 + q * 8];
    float bv[4];
#pragma unroll
    for (int tt = 0; tt < 4; ++tt) bv[tt] = bias[tt * 16 + mm];

    const int wid = threadIdx.x >> 6;
    const int gw = blockIdx.x * 4 + wid;
    const int nw = gridDim.x * 4;
    const int ntiles = M >> 4;

    for (int tile = gw; tile < ntiles; tile += nw) {
        const int row0 = tile << 4;
        const short8 a0 = *(const short8*)&xin[(size_t)(row0 + mm) * 64 + q * 8];
        const short8 a1 = *(const short8*)&xin[(size_t)(row0 + mm) * 64 + 32 + q * 8];
        f32x4 acc[8];
#pragma unroll
        for (int t = 0; t < 8; ++t) {
            acc[t] = (f32x4){0.f, 0.f, 0.f, 0.f};
            acc[t] = __builtin_amdgcn_mfma_f32_16x16x32_bf16(a0, bfrag[t][0], acc[t], 0, 0, 0);
            acc[t] = __builtin_amdgcn_mfma_f32_16x16x32_bf16(a1, bfrag[t][1], acc[t], 0, 0, 0);
        }
#pragma unroll
        for (int t = 0; t < 4; ++t) {
#pragma unroll
            for (int r = 0; r < 4; ++r) {
                const float v = acc[t][r];
                const float vn = __shfl_down(v, 1);
                if (!(mm & 1)) {
                    const unsigned int u = (unsigned int)f2bf(v) | ((unsigned int)f2bf(vn) << 16);
                    *(unsigned int*)&xw[(size_t)(row0 + q * 4 + r) * 64 + t * 16 + mm] = u;
                }
            }
        }
#pragma unroll
        for (int t = 4; t < 8; ++t) {
#pragma unroll
            for (int r = 0; r < 4; ++r) {
                const float v = acc[t][r] + bv[t - 4];
                const float vn = __shfl_down(v, 1);
                if (!(mm & 1)) {
                    const unsigned int u = (unsigned int)f2bf(v) | ((unsigned int)f2bf(vn) << 16);
                    *(unsigned int*)&xrb[(size_t)(row0 + q * 4 + r) * 64 + (t - 4) * 16 + mm] = u;
                }
            }
        }
    }
}

// ---------------- aggregate: out[i] = relu(mean_j xW[j] + xRb[i]) ----------
// One wave per node. Masked always-run 16-row unroll: 8 independent dword
// loads in flight for EVERY step including the tail (R7's remainder loop had
// 1 in flight and dominated for deg<16). Out-of-range rows load row 0
// (in-bounds, cache-hot) with weight 0.
__global__ __launch_bounds__(256) void aggregate(const unsigned short* __restrict__ xw,
                                                 const unsigned short* __restrict__ xrb,
                                                 const int* __restrict__ rowptr,
                                                 const int* __restrict__ bucket,
                                                 unsigned short* __restrict__ outb,
                                                 int N) {
    const int lane = threadIdx.x & 63;
    const int half = lane >> 5;
    const int fl = lane & 31;
    const int wid = threadIdx.x >> 6;
    const int gw = blockIdx.x * 4 + wid;
    const int nw = gridDim.x * 4;

    for (int i = gw; i < N; i += nw) {
        const int r0 = rowptr[i];
        const int dg = rowptr[i + 1] - r0;
        float lo0 = 0.f, lo1 = 0.f, lo2 = 0.f, lo3 = 0.f;
        float hi0 = 0.f, hi1 = 0.f, hi2 = 0.f, hi3 = 0.f;
        for (int base = 0; base < dg; base += 64) {
            int m = dg - base;
            if (m > 64) m = 64;
            const int s = (lane < m) ? bucket[r0 + base + lane] : 0;
            for (int t = 0; t < m; t += 16) {
                unsigned int u[8];
                float w[8];
#pragma unroll
                for (int p = 0; p < 8; ++p) {
                    const int jj = t + 2 * p;
                    const int ra = __shfl(s, jj), rb = __shfl(s, jj + 1);
                    const int rr = half ? rb : ra;
                    w[p] = ((jj + half) < m) ? 1.f : 0.f;
                    u[p] = *(const unsigned int*)&xw[(size_t)rr * 64 + fl * 2];
                }
                lo0 += w[0] * bflo(u[0]); hi0 += w[0] * bfhi(u[0]);
                lo1 += w[1] * bflo(u[1]); hi1 += w[1] * bfhi(u[1]);
                lo2 += w[2] * bflo(u[2]); hi2 += w[2] * bfhi(u[2]);
                lo3 += w[3] * bflo(u[3]); hi3 += w[3] * bfhi(u[3]);
                lo0 += w[4] * bflo(u[4]); hi0 += w[4] * bfhi(u[4]);
                lo1 += w[5] * bflo(u[5]); hi1 += w[5] * bfhi(u[5]);
                lo2 += w[6] * bflo(u[6]); hi2 += w[6] * bfhi(u[6]);
                lo3 += w[7] * bflo(u[7]); hi3 += w[7] * bfhi(u[7]);
            }
        }
        float lo = (lo0 + lo1) + (lo2 + lo3);
        float hi = (hi0 + hi1) + (hi2 + hi3);
        lo += __shfl_xor(lo, 32);
        hi += __shfl_xor(hi, 32);

        const float inv = 1.0f / (float)(dg > 0 ? dg : 1);
        const unsigned int ur = *(const unsigned int*)&xrb[(size_t)i * 64 + fl * 2];
        const float o0 = fmaxf(lo * inv + bflo(ur), 0.f);
        const float o1 = fmaxf(hi * inv + bfhi(ur), 0.f);
        if (half == 0) {
            const unsigned int u = (unsigned int)f2bf(o0) | ((unsigned int)f2bf(o1) << 16);
            *(unsigned int*)&outb[(size_t)i * 64 + fl * 2] = u;
        }
    }
}

// ---------------- Pooling: per-graph block, self-computed bounds ----------
__global__ __launch_bounds__(256) void pool_kernel(const unsigned short* __restrict__ h,
                                                   const int* __restrict__ batch,
                                                   float* __restrict__ pooled, int N) {
    __shared__ float red[16][64];
    __shared__ int bnds[2];
    const int gph = blockIdx.x;
    if (threadIdx.x < 2) {
        const int target = gph + threadIdx.x;
        int lo = 0, hi = N;
        while (lo < hi) {
            int mid = (lo + hi) >> 1;
            if (batch[mid] < target) lo = mid + 1; else hi = mid;
        }
        bnds[threadIdx.x] = lo;
    }
    __syncthreads();
    const int r0 = bnds[0], r1 = bnds[1];
    const int f = threadIdx.x & 15;
    const int r = threadIdx.x >> 4;
    float4 acc = {0.f, 0.f, 0.f, 0.f};
    for (int row = r0 + r; row < r1; row += 16) {
        const ushort4 v = *(const ushort4*)&h[(size_t)row * 64 + f * 4];
        acc.x += bf2f(v.x); acc.y += bf2f(v.y);
        acc.z += bf2f(v.z); acc.w += bf2f(v.w);
    }
    red[r][f * 4 + 0] = acc.x; red[r][f * 4 + 1] = acc.y;
    red[r][f * 4 + 2] = acc.z; red[r][f * 4 + 3] = acc.w;
    __syncthreads();
    if (threadIdx.x < 64) {
        float s = 0.f;
        for (int j = 0; j < 16; ++j) s += red[j][threadIdx.x];
        const int cnt = r1 - r0;
        const float invc = 1.0f / (float)(cnt > 0 ? cnt : 1);
        pooled[gph * 64 + threadIdx.x] = s * invc;
    }
}

// ---------------- Heads ----------------
__global__ __launch_bounds__(256) void head_kernel(const float* __restrict__ pooled,
                                                   const float* __restrict__ Wh,
                                                   const float* __restrict__ bh,
                                                   const float* __restrict__ Wc,
                                                   const float* __restrict__ bc,
                                                   const float* __restrict__ Wo,
                                                   const float* __restrict__ bo,
                                                   float* __restrict__ out) {
    __shared__ float pm[4096];
    __shared__ float hid[4096];
    __shared__ float lg[2048];
    const int t = threadIdx.x;

    for (int idx = t; idx < 4096; idx += 256) pm[idx] = pooled[idx];
    __syncthreads();

    for (int idx = t; idx < 4096; idx += 256) {
        int g = idx >> 6, o = idx & 63;
        float ah = bh[o], ac = bc[o];
        for (int k = 0; k < 64; ++k) {
            float p = pm[(g << 6) + k];
            ah += p * Wh[k * 64 + o];
            ac += p * Wc[k * 64 + o];
        }
        hid[idx] = ah;
        out[2048 + idx] = ah;
        out[6144 + idx] = ac;
    }
    __syncthreads();

    for (int idx = t; idx < 2048; idx += 256) {
        int g = idx >> 5, v = idx & 31;
        float a = bo[v];
        for (int k = 0; k < 64; ++k) a += hid[(g << 6) + k] * Wo[k * 32 + v];
        lg[idx] = a;
    }
    __syncthreads();

    if (t < 64) {
        float mx = -3.4e38f;
        for (int v = 0; v < 32; ++v) mx = fmaxf(mx, lg[(t << 5) + v]);
        float s = 0.f;
        for (int v = 0; v < 32; ++v) s += expf(lg[(t << 5) + v] - mx);
        float lse = mx + logf(s);
        for (int v = 0; v < 32; ++v) out[(t << 5) + v] = lg[(t << 5) + v] - lse;
    }
}

extern "C" void kernel_launch(void* const* d_in, const int* in_sizes, int n_in,
                              void* d_out, int out_size, void* d_ws, size_t ws_size,
                              hipStream_t stream) {
    const float* x = (const float*)d_in[0];
    const int* ei = (const int*)d_in[1];
    const int* batch = (const int*)d_in[2];
    const float* W1 = (const float*)d_in[3];
    const float* root1 = (const float*)d_in[4];
    const float* b1 = (const float*)d_in[5];
    const float* W2 = (const float*)d_in[6];
    const float* root2 = (const float*)d_in[7];
    const float* b2 = (const float*)d_in[8];
    const float* Wh = (const float*)d_in[9];
    const float* bh = (const float*)d_in[10];
    const float* Wc = (const float*)d_in[11];
    const float* bc = (const float*)d_in[12];
    const float* Wo = (const float*)d_in[13];
    const float* bo = (const float*)d_in[14];
    float* out = (float*)d_out;

    const int N = in_sizes[0] / 64;
    const int E = in_sizes[1] / 2;
    const int* srcp = ei;
    const int* dstp = ei + E;
    const int BINS = (N + (1 << RB) - 1) >> RB;

    char* ws = (char*)d_ws;
    size_t off = 0;
    auto alloc = [&](size_t bytes) -> void* {
        void* p = ws + off;
        off += (bytes + 255) & ~(size_t)255;
        return p;
    };
    int* rowptr = (int*)alloc((size_t)(N + 1) * 4);
    int* bucket = (int*)alloc((size_t)E * 4);
    unsigned short* xb = (unsigned short*)alloc((size_t)N * 64 * 2);  // reused as h2
    unsigned short* h1 = (unsigned short*)alloc((size_t)N * 64 * 2);
    size_t xw_bytes = (size_t)N * 64 * 2;
    size_t coarse_bytes = (size_t)BINS * CAP * 4;
    unsigned short* xw = (unsigned short*)alloc(xw_bytes > coarse_bytes ? xw_bytes : coarse_bytes);
    unsigned int* coarse = (unsigned int*)xw;  // coarse dead before gemm1 writes xw
    unsigned short* xrb = (unsigned short*)alloc((size_t)N * 64 * 2);
    unsigned short* bt = (unsigned short*)alloc(2 * 8192 * 2);
    float* pooled = (float*)alloc(4096 * 4);
    int* gcur = (int*)alloc(MAXBINS * 4);
    unsigned short* h2 = xb;

    const int n4 = N * 16;
    const int nbBin = (E + CHUNK - 1) / CHUNK;

    hipMemsetAsync(gcur, 0, MAXBINS * 4, stream);
    bin_edges<<<nbBin, 256, 0, stream>>>(srcp, dstp, coarse, gcur, E, BINS);
    finalize_csr<<<BINS, 256, 0, stream>>>(coarse, gcur, bucket, rowptr, N, E, BINS);

    prep_all<<<2 + (n4 + 255) / 256, 256, 0, stream>>>(x, xb, n4, W1, root1, W2, root2, bt);

    // layer 1
    gemm_xwr<<<1024, 256, 0, stream>>>(xb, bt, b1, xw, xrb, N);
    aggregate<<<2048, 256, 0, stream>>>(xw, xrb, rowptr, bucket, h1, N);
    // layer 2
    gemm_xwr<<<1024, 256, 0, stream>>>(h1, bt + 8192, b2, xw, xrb, N);
    aggregate<<<2048, 256, 0, stream>>>(xw, xrb, rowptr, bucket, h2, N);

    pool_kernel<<<64, 256, 0, stream>>>(h2, batch, pooled, N);
    head_kernel<<<1, 256, 0, stream>>>(pooled, Wh, bh, Wc, bc, Wo, bo, out);
}

// Round 9
// 298.158 us; speedup vs baseline: 5.0468x; 1.0434x over previous
//
#include <hip/hip_runtime.h>
#include <hip/hip_bf16.h>

// FEAT=EMB=HID=64, VOCAB=32, N_GRAPHS=64. N,E from in_sizes.
// R6: transform-first (xW = x@W once, then pure gather-mean).
// R7: CSR via two-level binning (coalesced writes only).
// R8: masked always-run 16-row unroll in aggregate.
// R9: PADDED CSR (segments multiple of 16, dummy -> zero row N of xw) makes
// the gather loop mask-free; single-shfl row broadcast halves bpermute count.

typedef __attribute__((ext_vector_type(8))) short short8;
typedef __attribute__((ext_vector_type(4))) float f32x4;

#define RB 9            // 512 nodes per coarse bin
#define MAXBINS 256     // N <= 131072
#define CAP 12288       // coarse per-bin capacity (raw count mean ~8192, 6sig~8732)
#define BCAP 14336      // padded per-bin bucket capacity (mean ~12032, 6sig~13200)
#define CHUNK 8192      // edges per bin_edges block

__device__ inline float bf2f(unsigned short h) {
    return __uint_as_float(((unsigned int)h) << 16);
}
__device__ inline float bflo(unsigned int u) { return __uint_as_float(u << 16); }
__device__ inline float bfhi(unsigned int u) { return __uint_as_float(u & 0xffff0000u); }
__device__ inline unsigned short f2bf(float f) {
    unsigned int u = __float_as_uint(f);
    u = (u + 0x7fffu + ((u >> 16) & 1u)) >> 16;  // RNE
    return (unsigned short)u;
}

// ---------------- fused: cast x -> bf16 + weight transpose prep -------------
__global__ __launch_bounds__(256) void prep_all(const float* __restrict__ x,
                                                unsigned short* __restrict__ xb, int n4,
                                                const float* __restrict__ W1,
                                                const float* __restrict__ R1,
                                                const float* __restrict__ W2,
                                                const float* __restrict__ R2,
                                                unsigned short* __restrict__ bt) {
    if (blockIdx.x < 2) {
        const float* W = blockIdx.x ? W2 : W1;
        const float* R = blockIdx.x ? R2 : R1;
        unsigned short* o = bt + (size_t)blockIdx.x * 8192;
        for (int idx = threadIdx.x; idx < 8192; idx += 256) {
            const int n = idx >> 6, k = idx & 63;
            const float v = (n < 64) ? W[k * 64 + n] : R[k * 64 + (n - 64)];
            o[idx] = f2bf(v);
        }
        return;
    }
    const int i = (blockIdx.x - 2) * 256 + threadIdx.x;
    if (i < n4) {
        const float4 v = ((const float4*)x)[i];
        ushort4 o;
        o.x = f2bf(v.x); o.y = f2bf(v.y); o.z = f2bf(v.z); o.w = f2bf(v.w);
        ((ushort4*)xb)[i] = o;
    }
}

// ---------------- CSR build phase 1: bin edges ----------------
__global__ __launch_bounds__(256) void bin_edges(const int* __restrict__ src,
                                                 const int* __restrict__ dst,
                                                 unsigned int* __restrict__ coarse,
                                                 int* __restrict__ gcur,
                                                 int E, int BINS) {
    __shared__ int cnt[MAXBINS];
    __shared__ int incl[MAXBINS];
    __shared__ int bstart[MAXBINS];
    __shared__ int bcur[MAXBINS];
    __shared__ int gbase[MAXBINS];
    __shared__ unsigned int stage[CHUNK];
    __shared__ unsigned char binOf[CHUNK];

    const int tid = threadIdx.x;
    const int chunk0 = blockIdx.x * CHUNK;
    int myS[32], myD[32];
#pragma unroll
    for (int k = 0; k < 32; ++k) {
        const int idx = chunk0 + k * 256 + tid;
        if (idx < E) { myS[k] = src[idx]; myD[k] = dst[idx]; }
        else myD[k] = -1;
    }
    cnt[tid] = 0;
    __syncthreads();
#pragma unroll
    for (int k = 0; k < 32; ++k)
        if (myD[k] >= 0) atomicAdd(&cnt[myD[k] >> RB], 1);
    __syncthreads();
    incl[tid] = cnt[tid];
    __syncthreads();
    for (int off = 1; off < 256; off <<= 1) {
        int t = (tid >= off) ? incl[tid - off] : 0;
        __syncthreads();
        incl[tid] += t;
        __syncthreads();
    }
    bstart[tid] = incl[tid] - cnt[tid];
    bcur[tid] = incl[tid] - cnt[tid];
    __syncthreads();
#pragma unroll
    for (int k = 0; k < 32; ++k) {
        if (myD[k] >= 0) {
            const int b = myD[k] >> RB;
            const int pos = atomicAdd(&bcur[b], 1);
            stage[pos] = (unsigned int)myS[k] | ((unsigned int)(myD[k] & ((1 << RB) - 1)) << 17);
            binOf[pos] = (unsigned char)b;
        }
    }
    __syncthreads();
    if (tid < BINS && cnt[tid] > 0)
        gbase[tid] = tid * CAP + atomicAdd(&gcur[tid], cnt[tid]);
    __syncthreads();
    int total = E - chunk0;
    if (total > CHUNK) total = CHUNK;
    for (int idx = tid; idx < total; idx += 256) {
        const int b = binOf[idx];
        coarse[gbase[b] + (idx - bstart[b])] = stage[idx];
    }
}

// ---------------- CSR build phase 2: padded CSR per bin ----------------
// Each node's segment padded to a multiple of 16; dummy slots hold index N
// (zero row of xw). Per-bin bucket region is fixed at b*BCAP.
__global__ __launch_bounds__(256) void finalize_csr(const unsigned int* __restrict__ coarse,
                                                    const int* __restrict__ gcur,
                                                    int* __restrict__ bucket,
                                                    int* __restrict__ pstart,
                                                    int* __restrict__ degarr,
                                                    int N, int BINS) {
    __shared__ int ncnt[512];
    __shared__ int pexcl[512];
    __shared__ int ncur[512];
    __shared__ int s2[256];
    __shared__ unsigned int st[BCAP];
    __shared__ int ptot;

    const int b = blockIdx.x;
    const int tid = threadIdx.x;
    const int cb = gcur[b];
    const int base = b * BCAP;
    const unsigned int* reg = coarse + (size_t)b * CAP;
    const int node0 = b << RB;
    int nloc = N - node0;
    if (nloc > 512) nloc = 512;

    ncnt[tid] = 0; ncnt[tid + 256] = 0;
    __syncthreads();
    for (int idx = tid; idx < cb; idx += 256)
        atomicAdd(&ncnt[reg[idx] >> 17], 1);
    __syncthreads();
    // padded counts, pair-wise exclusive scan over 512
    const int p0 = (ncnt[2 * tid] + 15) & ~15;
    const int p1 = (ncnt[2 * tid + 1] + 15) & ~15;
    s2[tid] = p0 + p1;
    __syncthreads();
    for (int off = 1; off < 256; off <<= 1) {
        int t = (tid >= off) ? s2[tid - off] : 0;
        __syncthreads();
        s2[tid] += t;
        __syncthreads();
    }
    const int pairExcl = s2[tid] - (p0 + p1);
    pexcl[2 * tid] = pairExcl;
    pexcl[2 * tid + 1] = pairExcl + p0;
    ncur[2 * tid] = pairExcl;
    ncur[2 * tid + 1] = pairExcl + p0;
    if (tid == 255) ptot = s2[255];
    __syncthreads();
    const int total = ptot;
    // init padded staging with dummy index N
    for (int idx = tid; idx < total; idx += 256) st[idx] = (unsigned int)N;
    // pstart/deg (coalesced)
    for (int i = tid; i < nloc; i += 256) {
        pstart[node0 + i] = base + pexcl[i];
        degarr[node0 + i] = ncnt[i];
    }
    __syncthreads();
    for (int idx = tid; idx < cb; idx += 256) {
        const unsigned int e = reg[idx];
        const int p = atomicAdd(&ncur[e >> 17], 1);
        st[p] = e & 0x1FFFFu;
    }
    __syncthreads();
    for (int idx = tid; idx < total; idx += 256) bucket[base + idx] = (int)st[idx];
}

// ---------------- dense GEMM: y = x @ [W | R], bias folded into R half -----
// Block 0 also zeroes xw row M (the dummy row for padded gathers).
__global__ __launch_bounds__(256) void gemm_xwr(const unsigned short* __restrict__ xin,
                                                const unsigned short* __restrict__ bt,
                                                const float* __restrict__ bias,
                                                unsigned short* __restrict__ xw,
                                                unsigned short* __restrict__ xrb,
                                                int M) {
    if (blockIdx.x == 0 && threadIdx.x < 32)
        *(unsigned int*)&xw[(size_t)M * 64 + threadIdx.x * 2] = 0u;

    const int lane = threadIdx.x & 63;
    const int q = lane >> 4;
    const int mm = lane & 15;

    short8 bfrag[8][2];
#pragma unroll
    for (int t = 0; t < 8; ++t)
#pragma unroll
        for (int c = 0; c < 2; ++c)
            bfrag[t][c] = *(const short8*)&bt[(size_t)(t * 16 + mm) * 64 + c * 32 + q * 8];
    float bv[4];
#pragma unroll
    for (int tt = 0; tt < 4; ++tt) bv[tt] = bias[tt * 16 + mm];

    const int wid = threadIdx.x >> 6;
    const int gw = blockIdx.x * 4 + wid;
    const int nw = gridDim.x * 4;
    const int ntiles = M >> 4;

    for (int tile = gw; tile < ntiles; tile += nw) {
        const int row0 = tile << 4;
        const short8 a0 = *(const short8*)&xin[(size_t)(row0 + mm) * 64 + q * 8];
        const short8 a1 = *(const short8*)&xin[(size_t)(row0 + mm) * 64 + 32 + q * 8];
        f32x4 acc[8];
#pragma unroll
        for (int t = 0; t < 8; ++t) {
            acc[t] = (f32x4){0.f, 0.f, 0.f, 0.f};
            acc[t] = __builtin_amdgcn_mfma_f32_16x16x32_bf16(a0, bfrag[t][0], acc[t], 0, 0, 0);
            acc[t] = __builtin_amdgcn_mfma_f32_16x16x32_bf16(a1, bfrag[t][1], acc[t], 0, 0, 0);
        }
#pragma unroll
        for (int t = 0; t < 4; ++t) {
#pragma unroll
            for (int r = 0; r < 4; ++r) {
                const float v = acc[t][r];
                const float vn = __shfl_down(v, 1);
                if (!(mm & 1)) {
                    const unsigned int u = (unsigned int)f2bf(v) | ((unsigned int)f2bf(vn) << 16);
                    *(unsigned int*)&xw[(size_t)(row0 + q * 4 + r) * 64 + t * 16 + mm] = u;
                }
            }
        }
#pragma unroll
        for (int t = 4; t < 8; ++t) {
#pragma unroll
            for (int r = 0; r < 4; ++r) {
                const float v = acc[t][r] + bv[t - 4];
                const float vn = __shfl_down(v, 1);
                if (!(mm & 1)) {
                    const unsigned int u = (unsigned int)f2bf(v) | ((unsigned int)f2bf(vn) << 16);
                    *(unsigned int*)&xrb[(size_t)(row0 + q * 4 + r) * 64 + (t - 4) * 16 + mm] = u;
                }
            }
        }
    }
}

// ---------------- aggregate: out[i] = relu(mean_j xW[j] + xRb[i]) ----------
// Padded segments: no masks in the hot loop; one bpermute per row; 8 dword
// loads (16 rows) in flight per step.
__global__ __launch_bounds__(256) void aggregate(const unsigned short* __restrict__ xw,
                                                 const unsigned short* __restrict__ xrb,
                                                 const int* __restrict__ pstart,
                                                 const int* __restrict__ degarr,
                                                 const int* __restrict__ bucket,
                                                 unsigned short* __restrict__ outb,
                                                 int N) {
    const int lane = threadIdx.x & 63;
    const int half = lane >> 5;
    const int fl = lane & 31;
    const int wid = threadIdx.x >> 6;
    const int gw = blockIdx.x * 4 + wid;
    const int nw = gridDim.x * 4;

    for (int i = gw; i < N; i += nw) {
        const int r0 = pstart[i];
        const int dg = degarr[i];
        const int pdeg = (dg + 15) & ~15;
        float lo0 = 0.f, lo1 = 0.f, lo2 = 0.f, lo3 = 0.f;
        float hi0 = 0.f, hi1 = 0.f, hi2 = 0.f, hi3 = 0.f;
        for (int base = 0; base < pdeg; base += 64) {
            const int rem = pdeg - base;
            const int s = (lane < rem) ? bucket[r0 + base + lane] : N;
            const int mm = rem < 64 ? rem : 64;
            for (int t = 0; t < mm; t += 16) {
                unsigned int u[8];
#pragma unroll
                for (int p = 0; p < 8; ++p) {
                    const int rr = __shfl(s, t + 2 * p + half);
                    u[p] = *(const unsigned int*)&xw[(size_t)rr * 64 + fl * 2];
                }
                lo0 += bflo(u[0]); hi0 += bfhi(u[0]);
                lo1 += bflo(u[1]); hi1 += bfhi(u[1]);
                lo2 += bflo(u[2]); hi2 += bfhi(u[2]);
                lo3 += bflo(u[3]); hi3 += bfhi(u[3]);
                lo0 += bflo(u[4]); hi0 += bfhi(u[4]);
                lo1 += bflo(u[5]); hi1 += bfhi(u[5]);
                lo2 += bflo(u[6]); hi2 += bfhi(u[6]);
                lo3 += bflo(u[7]); hi3 += bfhi(u[7]);
            }
        }
        float lo = (lo0 + lo1) + (lo2 + lo3);
        float hi = (hi0 + hi1) + (hi2 + hi3);
        lo += __shfl_xor(lo, 32);
        hi += __shfl_xor(hi, 32);

        const float inv = 1.0f / (float)(dg > 0 ? dg : 1);
        const unsigned int ur = *(const unsigned int*)&xrb[(size_t)i * 64 + fl * 2];
        const float o0 = fmaxf(lo * inv + bflo(ur), 0.f);
        const float o1 = fmaxf(hi * inv + bfhi(ur), 0.f);
        if (half == 0) {
            const unsigned int u = (unsigned int)f2bf(o0) | ((unsigned int)f2bf(o1) << 16);
            *(unsigned int*)&outb[(size_t)i * 64 + fl * 2] = u;
        }
    }
}

// ---------------- Pooling: per-graph block, self-computed bounds ----------
__global__ __launch_bounds__(256) void pool_kernel(const unsigned short* __restrict__ h,
                                                   const int* __restrict__ batch,
                                                   float* __restrict__ pooled, int N) {
    __shared__ float red[16][64];
    __shared__ int bnds[2];
    const int gph = blockIdx.x;
    if (threadIdx.x < 2) {
        const int target = gph + threadIdx.x;
        int lo = 0, hi = N;
        while (lo < hi) {
            int mid = (lo + hi) >> 1;
            if (batch[mid] < target) lo = mid + 1; else hi = mid;
        }
        bnds[threadIdx.x] = lo;
    }
    __syncthreads();
    const int r0 = bnds[0], r1 = bnds[1];
    const int f = threadIdx.x & 15;
    const int r = threadIdx.x >> 4;
    float4 acc = {0.f, 0.f, 0.f, 0.f};
    for (int row = r0 + r; row < r1; row += 16) {
        const ushort4 v = *(const ushort4*)&h[(size_t)row * 64 + f * 4];
        acc.x += bf2f(v.x); acc.y += bf2f(v.y);
        acc.z += bf2f(v.z); acc.w += bf2f(v.w);
    }
    red[r][f * 4 + 0] = acc.x; red[r][f * 4 + 1] = acc.y;
    red[r][f * 4 + 2] = acc.z; red[r][f * 4 + 3] = acc.w;
    __syncthreads();
    if (threadIdx.x < 64) {
        float s = 0.f;
        for (int j = 0; j < 16; ++j) s += red[j][threadIdx.x];
        const int cnt = r1 - r0;
        const float invc = 1.0f / (float)(cnt > 0 ? cnt : 1);
        pooled[gph * 64 + threadIdx.x] = s * invc;
    }
}

// ---------------- Heads ----------------
__global__ __launch_bounds__(256) void head_kernel(const float* __restrict__ pooled,
                                                   const float* __restrict__ Wh,
                                                   const float* __restrict__ bh,
                                                   const float* __restrict__ Wc,
                                                   const float* __restrict__ bc,
                                                   const float* __restrict__ Wo,
                                                   const float* __restrict__ bo,
                                                   float* __restrict__ out) {
    __shared__ float pm[4096];
    __shared__ float hid[4096];
    __shared__ float lg[2048];
    const int t = threadIdx.x;

    for (int idx = t; idx < 4096; idx += 256) pm[idx] = pooled[idx];
    __syncthreads();

    for (int idx = t; idx < 4096; idx += 256) {
        int g = idx >> 6, o = idx & 63;
        float ah = bh[o], ac = bc[o];
        for (int k = 0; k < 64; ++k) {
            float p = pm[(g << 6) + k];
            ah += p * Wh[k * 64 + o];
            ac += p * Wc[k * 64 + o];
        }
        hid[idx] = ah;
        out[2048 + idx] = ah;
        out[6144 + idx] = ac;
    }
    __syncthreads();

    for (int idx = t; idx < 2048; idx += 256) {
        int g = idx >> 5, v = idx & 31;
        float a = bo[v];
        for (int k = 0; k < 64; ++k) a += hid[(g << 6) + k] * Wo[k * 32 + v];
        lg[idx] = a;
    }
    __syncthreads();

    if (t < 64) {
        float mx = -3.4e38f;
        for (int v = 0; v < 32; ++v) mx = fmaxf(mx, lg[(t << 5) + v]);
        float s = 0.f;
        for (int v = 0; v < 32; ++v) s += expf(lg[(t << 5) + v] - mx);
        float lse = mx + logf(s);
        for (int v = 0; v < 32; ++v) out[(t << 5) + v] = lg[(t << 5) + v] - lse;
    }
}

extern "C" void kernel_launch(void* const* d_in, const int* in_sizes, int n_in,
                              void* d_out, int out_size, void* d_ws, size_t ws_size,
                              hipStream_t stream) {
    const float* x = (const float*)d_in[0];
    const int* ei = (const int*)d_in[1];
    const int* batch = (const int*)d_in[2];
    const float* W1 = (const float*)d_in[3];
    const float* root1 = (const float*)d_in[4];
    const float* b1 = (const float*)d_in[5];
    const float* W2 = (const float*)d_in[6];
    const float* root2 = (const float*)d_in[7];
    const float* b2 = (const float*)d_in[8];
    const float* Wh = (const float*)d_in[9];
    const float* bh = (const float*)d_in[10];
    const float* Wc = (const float*)d_in[11];
    const float* bc = (const float*)d_in[12];
    const float* Wo = (const float*)d_in[13];
    const float* bo = (const float*)d_in[14];
    float* out = (float*)d_out;

    const int N = in_sizes[0] / 64;
    const int E = in_sizes[1] / 2;
    const int* srcp = ei;
    const int* dstp = ei + E;
    const int BINS = (N + (1 << RB) - 1) >> RB;

    char* ws = (char*)d_ws;
    size_t off = 0;
    auto alloc = [&](size_t bytes) -> void* {
        void* p = ws + off;
        off += (bytes + 255) & ~(size_t)255;
        return p;
    };
    int* pstart = (int*)alloc((size_t)N * 4);
    int* degarr = (int*)alloc((size_t)N * 4);
    int* bucket = (int*)alloc((size_t)BINS * BCAP * 4);
    unsigned short* xb = (unsigned short*)alloc((size_t)N * 64 * 2);  // reused as h2
    unsigned short* h1 = (unsigned short*)alloc((size_t)N * 64 * 2);
    size_t xw_bytes = (size_t)(N + 1) * 64 * 2;  // +1: zero row for dummies
    size_t coarse_bytes = (size_t)BINS * CAP * 4;
    unsigned short* xw = (unsigned short*)alloc(xw_bytes > coarse_bytes ? xw_bytes : coarse_bytes);
    unsigned int* coarse = (unsigned int*)xw;  // coarse dead before gemm1 writes xw
    unsigned short* xrb = (unsigned short*)alloc((size_t)N * 64 * 2);
    unsigned short* bt = (unsigned short*)alloc(2 * 8192 * 2);
    float* pooled = (float*)alloc(4096 * 4);
    int* gcur = (int*)alloc(MAXBINS * 4);
    unsigned short* h2 = xb;

    const int n4 = N * 16;
    const int nbBin = (E + CHUNK - 1) / CHUNK;

    hipMemsetAsync(gcur, 0, MAXBINS * 4, stream);
    bin_edges<<<nbBin, 256, 0, stream>>>(srcp, dstp, coarse, gcur, E, BINS);
    finalize_csr<<<BINS, 256, 0, stream>>>(coarse, gcur, bucket, pstart, degarr, N, BINS);

    prep_all<<<2 + (n4 + 255) / 256, 256, 0, stream>>>(x, xb, n4, W1, root1, W2, root2, bt);

    // layer 1
    gemm_xwr<<<1024, 256, 0, stream>>>(xb, bt, b1, xw, xrb, N);
    aggregate<<<4096, 256, 0, stream>>>(xw, xrb, pstart, degarr, bucket, h1, N);
    // layer 2
    gemm_xwr<<<1024, 256, 0, stream>>>(h1, bt + 8192, b2, xw, xrb, N);
    aggregate<<<4096, 256, 0, stream>>>(xw, xrb, pstart, degarr, bucket, h2, N);

    pool_kernel<<<64, 256, 0, stream>>>(h2, batch, pooled, N);
    head_kernel<<<1, 256, 0, stream>>>(pooled, Wh, bh, Wc, bc, Wo, bo, out);
}